// Round 1
// baseline (299.698 us; speedup 1.0000x reference)
//
#include <hip/hip_runtime.h>
#include <stdint.h>

typedef unsigned short ushort_t;
typedef __attribute__((ext_vector_type(8))) short short8;   // 8 bf16 = 4 VGPRs
typedef __attribute__((ext_vector_type(4))) float float4v;  // MFMA acc

#define N_NODES 100000
#define N_EDGES 1600000
#define D 128
#define NB_GEMM 1563   // (N_NODES+63)/64
#define NB_CNT  1563   // (N_EDGES+1023)/1024, 4 edges/thread

static __device__ __forceinline__ float bf2f(uint32_t u) {
    return __builtin_bit_cast(float, u << 16);
}
static __device__ __forceinline__ ushort_t f2bf(float f) {
    uint32_t u = __builtin_bit_cast(uint32_t, f);
    uint32_t r = u + 0x7fffu + ((u >> 16) & 1u);   // RNE
    return (ushort_t)(r >> 16);
}
// leaky_relu(0.2) -> clip(-2,2) -> exp
static __device__ __forceinline__ float edge_e(float s) {
    float x = (s >= 0.0f) ? s : 0.2f * s;
    x = fminf(fmaxf(x, -2.0f), 2.0f);
    return __expf(x);
}

// ---------------- prep: zero cnt | W -> fragment-ordered bf16 WT | detect | wa
// grid 391 x 256.  All blocks zero cnt; blocks 0-63 convert W to MFMA-fragment
// order (16384 elems); block 64 detects edge dtype; block 65 computes wa.
// Fragment order: element (k,n) of W^T-as-B goes to
//   WT[ ((kb*8 + t)*64 + q*16 + l)*8 + j ]
// with kb=k>>5, q=(k>>3)&3, j=k&7, t=n>>4, l=n&15 — so in mega1 a wave's
// B-frag for (kb,t) is one coalesced 16B load at ((kb*8+t)*64 + lane)*8.
__global__ void __launch_bounds__(256) prep_kernel(int* __restrict__ cnt, int n,
                                                   const float* __restrict__ W,
                                                   const float* __restrict__ KA,
                                                   float* __restrict__ wa,
                                                   ushort_t* __restrict__ WT,
                                                   const int* __restrict__ E,
                                                   int* __restrict__ eflag) {
    __shared__ int s;
    int b = blockIdx.x, t = threadIdx.x;
    int i = b * 256 + t;
    if (i < n) cnt[i] = 0;
    if (b < 64) {                                   // fragment-order + bf16
        int k = i >> 7, nn = i & 127;
        int kb = k >> 5, q = (k >> 3) & 3, j = k & 7;
        int tt = nn >> 4, l = nn & 15;
        WT[((kb * 8 + tt) * 64 + q * 16 + l) * 8 + j] = f2bf(W[i]);
    } else if (b == 64) {                           // edge dtype detect
        if (t == 0) s = 0;
        __syncthreads();
        int nz = 0;
#pragma unroll
        for (int j = 0; j < 8; j++)
            if (E[(t + j * 256) * 2 + 1] != 0) nz = 1;
        if (nz) atomicOr(&s, 1);
        __syncthreads();
        if (t == 0) *eflag = (s == 0) ? 1 : 0;
    } else if (b == 65) {                           // wa = W @ ka (fp32 exact)
        int half = t >> 7, k = t & 127;
        const float* kav = KA + half * 128;
        const float* wrow = W + k * 128;
        float acc = 0.0f;
#pragma unroll 8
        for (int j = 0; j < 128; j++) acc += wrow[j] * kav[j];
        wa[half * 128 + k] = acc;
    }
}

// ---------------- mega1: [blocks 0..1562] MFMA gemm + fused score ------------
//                  [blocks 1563..3125] count, 4 edges/thread ------------------
__global__ void __launch_bounds__(256) mega1_kernel(const float* __restrict__ X,
                                                    const ushort_t* __restrict__ WT,
                                                    const float* __restrict__ wa,
                                                    ushort_t* __restrict__ H,
                                                    float* __restrict__ st,
                                                    float* __restrict__ ss,
                                                    int M,
                                                    const int* __restrict__ E,
                                                    const int* __restrict__ eflag,
                                                    int* __restrict__ cnt,
                                                    int* __restrict__ rank, int ne) {
    // per-wave output staging: 16 rows x 128 cols bf16, +8 pad. 17.4 KB total.
    __shared__ ushort_t ob[4][16 * 136];
    if (blockIdx.x >= NB_GEMM) {
        // ---------------- count branch: 4 independent chains/thread ---------
        int base = (blockIdx.x - NB_GEMM) * 1024 + threadIdx.x;
        int i64 = *eflag;                     // wave-uniform
#pragma unroll
        for (int j = 0; j < 4; j++) {
            int i = base + j * 256;
            if (i < ne) {
                int tgt = i64 ? E[i * 4] : E[i * 2];
                if ((unsigned)tgt >= (unsigned)N_NODES) tgt = 0;
                rank[i] = atomicAdd(&cnt[tgt], 1);
            }
        }
        return;
    }
    // ---------------- gemm + score branch (no B staging, no barrier) --------
    int tid = threadIdx.x;
    int wave = tid >> 6, lane = tid & 63;
    int quad = lane >> 4, l16 = lane & 15;
    int m0 = blockIdx.x * 64 + wave * 16;

    int arow = m0 + l16; if (arow >= M) arow = M - 1;   // clamp; stores guarded
    const float* xrow = X + (size_t)arow * D + quad * 8;
    short8 a[4];
    float sct = 0.0f, scs = 0.0f;             // fp32 score partials (exact path)
#pragma unroll
    for (int kb = 0; kb < 4; kb++) {          // A[m=l16][k=kb*32+quad*8+j]
        float4 f0 = *(const float4*)(xrow + kb * 32);
        float4 f1 = *(const float4*)(xrow + kb * 32 + 4);
        const float* wt0 = wa + kb * 32 + quad * 8;
        float4 t0 = *(const float4*)(wt0);
        float4 t1 = *(const float4*)(wt0 + 4);
        float4 s0 = *(const float4*)(wt0 + 128);
        float4 s1 = *(const float4*)(wt0 + 132);
        sct += f0.x * t0.x + f0.y * t0.y + f0.z * t0.z + f0.w * t0.w
             + f1.x * t1.x + f1.y * t1.y + f1.z * t1.z + f1.w * t1.w;
        scs += f0.x * s0.x + f0.y * s0.y + f0.z * s0.z + f0.w * s0.w
             + f1.x * s1.x + f1.y * s1.y + f1.z * s1.z + f1.w * s1.w;
        short8 v;
        v[0] = (short)f2bf(f0.x); v[1] = (short)f2bf(f0.y);
        v[2] = (short)f2bf(f0.z); v[3] = (short)f2bf(f0.w);
        v[4] = (short)f2bf(f1.x); v[5] = (short)f2bf(f1.y);
        v[6] = (short)f2bf(f1.z); v[7] = (short)f2bf(f1.w);
        a[kb] = v;
    }
    // reduce score over quads (lanes l16, l16+16, l16+32, l16+48)
    sct += __shfl_xor(sct, 16); sct += __shfl_xor(sct, 32);
    scs += __shfl_xor(scs, 16); scs += __shfl_xor(scs, 32);
    if (quad == 0 && m0 + l16 < M) { st[m0 + l16] = sct; ss[m0 + l16] = scs; }

    // B direct from global (WT is 32 KB, L1/L2-resident, fragment-ordered)
    const short8* Bf = (const short8*)WT;
    float4v acc[8] = {};
#pragma unroll
    for (int kb = 0; kb < 4; kb++) {
#pragma unroll
        for (int t = 0; t < 8; t++) {         // B[k=kb*32+quad*8+j][n=t*16+l16]
            short8 b = Bf[(kb * 8 + t) * 64 + lane];
            acc[t] = __builtin_amdgcn_mfma_f32_16x16x32_bf16(a[kb], b, acc[t], 0, 0, 0);
        }
    }
    // C/D: col = lane&15, row = quad*4 + reg   [m89-verified]
    // stage to LDS (scalar b16 writes), then coalesced 16B global stores
    ushort_t* obw = ob[wave];
#pragma unroll
    for (int t = 0; t < 8; t++)
#pragma unroll
        for (int r = 0; r < 4; r++)
            obw[(quad * 4 + r) * 136 + t * 16 + l16] = f2bf(acc[t][r]);
    __syncthreads();                          // block-uniform in this branch
#pragma unroll
    for (int p = 0; p < 4; p++) {
        int row = p * 4 + quad;               // 4 rows/pass, 16 lanes/row
        int orow = m0 + row;
        if (orow < M) {
            uint4 v = *(const uint4*)(&obw[row * 136 + l16 * 8]);
            *(uint4*)(H + (size_t)orow * D + l16 * 8) = v;
        }
    }
}

// ---------------- scan pass 1: block-local exclusive (writes i<=n) -----------
__global__ void __launch_bounds__(256) scan1_kernel(const int* __restrict__ cnt,
                                                    int* __restrict__ rowp,
                                                    int* __restrict__ bsum, int n) {
    __shared__ int lds[256];
    int t = threadIdx.x;
    int i = blockIdx.x * 256 + t;
    int v = (i < n) ? cnt[i] : 0;
    lds[t] = v;
    __syncthreads();
    for (int off = 1; off < 256; off <<= 1) {        // Hillis-Steele inclusive
        int x = (t >= off) ? lds[t - off] : 0;
        __syncthreads();
        lds[t] += x;
        __syncthreads();
    }
    if (i <= n) rowp[i] = lds[t] - v;                // partial exclusive
    if (t == 255) bsum[blockIdx.x] = lds[255];       // block total
}

// ---------------- scan pass 2: exclusive-scan the 391 block sums -------------
__global__ void __launch_bounds__(512) scan2_kernel(int* __restrict__ bsum, int nb) {
    __shared__ int lds[512];
    int t = threadIdx.x;
    int v = (t < nb) ? bsum[t] : 0;
    lds[t] = v;
    __syncthreads();
    for (int off = 1; off < 512; off <<= 1) {
        int x = (t >= off) ? lds[t - off] : 0;
        __syncthreads();
        lds[t] += x;
        __syncthreads();
    }
    if (t < nb) bsum[t] = lds[t] - v;                // exclusive block offset
}

// ---------------- fill CSR: atomic-free; final offset = rowp+bsum ------------
__global__ void fill_kernel(const int* __restrict__ E, const int* __restrict__ eflag,
                            const int* __restrict__ rowp, const int* __restrict__ bsum,
                            const int* __restrict__ rank,
                            int* __restrict__ csr_src, int ne) {
    int i = blockIdx.x * blockDim.x + threadIdx.x;
    if (i >= ne) return;
    int i64 = *eflag;                          // wave-uniform
    int tgt, src;
    if (i64) { tgt = E[i * 4]; src = E[i * 4 + 2]; }
    else     { tgt = E[i * 2]; src = E[i * 2 + 1]; }
    if ((unsigned)tgt >= (unsigned)N_NODES) tgt = 0;
    if ((unsigned)src >= (unsigned)N_NODES) src = 0;
    csr_src[rowp[tgt] + bsum[tgt >> 8] + rank[i]] = src;
}

// ---------------- aggregation: 4 edges in flight per wave --------------------
__global__ void __launch_bounds__(256) agg_kernel(const int* __restrict__ rowp,
                                                  const int* __restrict__ bsum,
                                                  const int* __restrict__ csr_src,
                                                  const float* __restrict__ st,
                                                  const float* __restrict__ ss,
                                                  const ushort_t* __restrict__ H,
                                                  float* __restrict__ out, int n) {
    int wave = threadIdx.x >> 6, lane = threadIdx.x & 63;
    int node = blockIdx.x * 4 + wave;
    if (node >= n) return;
    node = __builtin_amdgcn_readfirstlane(node);  // scalarize rowp/st loads
    int g = lane >> 4, l = lane & 15;
    int start = rowp[node] + bsum[node >> 8];
    int end   = rowp[node + 1] + bsum[(node + 1) >> 8];
    float stn = st[node];
    float den = 0.0f;
    float acc[8] = {};
    for (int m = start + g; m < end; m += 4) {
        int src = csr_src[m];                     // group-uniform
        float e = edge_e(stn + ss[src]);
        den += e;
        uint4 p = *(const uint4*)(H + (size_t)src * D + l * 8);  // 8 bf16
        acc[0] += e * bf2f(p.x & 0xffff); acc[1] += e * bf2f(p.x >> 16);
        acc[2] += e * bf2f(p.y & 0xffff); acc[3] += e * bf2f(p.y >> 16);
        acc[4] += e * bf2f(p.z & 0xffff); acc[5] += e * bf2f(p.z >> 16);
        acc[6] += e * bf2f(p.w & 0xffff); acc[7] += e * bf2f(p.w >> 16);
    }
    den += __shfl_xor(den, 16);
    den += __shfl_xor(den, 32);
#pragma unroll
    for (int j = 0; j < 8; j++) {
        acc[j] += __shfl_xor(acc[j], 16);
        acc[j] += __shfl_xor(acc[j], 32);
    }
    float inv = 1.0f / (den + 1e-9f);
    if (g == 0) {                                 // 16 lanes store 512B row
        float4 o0 = make_float4(acc[0] * inv, acc[1] * inv, acc[2] * inv, acc[3] * inv);
        float4 o1 = make_float4(acc[4] * inv, acc[5] * inv, acc[6] * inv, acc[7] * inv);
        *(float4*)(out + (size_t)node * D + l * 8) = o0;
        *(float4*)(out + (size_t)node * D + l * 8 + 4) = o1;
    }
}

extern "C" void kernel_launch(void* const* d_in, const int* in_sizes, int n_in,
                              void* d_out, int out_size, void* d_ws, size_t ws_size,
                              hipStream_t stream) {
    const float* X  = (const float*)d_in[0];
    const int*   E  = (const int*)d_in[1];
    const float* W  = (const float*)d_in[2];
    const float* KA = (const float*)d_in[3];
    for (int i = 0; i < n_in; i++) {
        int s = in_sizes[i];
        if (s == N_NODES * D)      X  = (const float*)d_in[i];
        else if (s == N_EDGES * 2) E  = (const int*)d_in[i];
        else if (s == D * D)       W  = (const float*)d_in[i];
        else if (s == 2 * D)       KA = (const float*)d_in[i];
    }
    float* out = (float*)d_out;                // fp32 [100000,128]
    int* rank = (int*)d_out;                   // 6.4 MB scratch in d_out head

    char* ws = (char*)d_ws;
    // workspace layout (16B aligned), total ~33.6 MB
    ushort_t* H        = (ushort_t*)(ws + 0);           // 25,600,000 B (bf16 h)
    float*    wa       = (float*)   (ws + 25600000);    //      1,024 B
    float*    st       = (float*)   (ws + 25601024);    //    400,000 B
    float*    ssb      = (float*)   (ws + 26001024);    //    400,000 B
    int*      cnt      = (int*)     (ws + 26401024);    //    400,000 B
    int*      rowp     = (int*)     (ws + 26801024);    //    400,016 B
    int*      csrs     = (int*)     (ws + 27201040);    //  6,400,000 B
    int*      eflag    = (int*)     (ws + 33601040);    //         16 B
    int*      bsum     = (int*)     (ws + 33601056);    //      1,600 B
    ushort_t* WT       = (ushort_t*)(ws + 33602656);    //     32,768 B

    const int NB_NODE = (N_NODES + 255) / 256;          // 391
    const int NB_WAVE = (N_NODES + 3) / 4;              // 25000 (1 wave/node)
    const int NB_EDGE = (N_EDGES + 255) / 256;          // 6250 (fill)

    prep_kernel<<<NB_NODE, 256, 0, stream>>>(cnt, N_NODES, W, KA, wa, WT, E, eflag);
    mega1_kernel<<<NB_GEMM + NB_CNT, 256, 0, stream>>>(X, WT, wa, H, st, ssb,
                                                       N_NODES, E, eflag, cnt,
                                                       rank, N_EDGES);
    scan1_kernel<<<NB_NODE, 256, 0, stream>>>(cnt, rowp, bsum, N_NODES);
    scan2_kernel<<<1, 512, 0, stream>>>(bsum, NB_NODE);
    fill_kernel<<<NB_EDGE, 256, 0, stream>>>(E, eflag, rowp, bsum, rank, csrs, N_EDGES);
    agg_kernel<<<NB_WAVE, 256, 0, stream>>>(rowp, bsum, csrs, st, ssb, H, out, N_NODES);
}

// Round 4
// 240.963 us; speedup vs baseline: 1.2438x; 1.2438x over previous
//
#include <hip/hip_runtime.h>
#include <stdint.h>

typedef unsigned short ushort_t;
typedef __attribute__((ext_vector_type(8))) short short8;   // 8 bf16 = 4 VGPRs
typedef __attribute__((ext_vector_type(4))) float float4v;  // MFMA acc

#define N_NODES 100000
#define N_EDGES 1600000
#define D 128
#define NB_GEMM 1563   // (N_NODES+63)/64
#define NB_B1   250    // edge-bucket blocks
#define EPB     6400   // edges per B1 block: 250*6400 = 1,600,000 = 25*256 each
#define BUCKETS 782    // ceil(100000/128), 128 nodes per bucket

static __device__ __forceinline__ float bf2f(uint32_t u) {
    return __builtin_bit_cast(float, u << 16);
}
static __device__ __forceinline__ ushort_t f2bf(float f) {
    uint32_t u = __builtin_bit_cast(uint32_t, f);
    uint32_t r = u + 0x7fffu + ((u >> 16) & 1u);   // RNE
    return (ushort_t)(r >> 16);
}
// leaky_relu(0.2) -> clip(-2,2) -> exp
static __device__ __forceinline__ float edge_e(float s) {
    float x = (s >= 0.0f) ? s : 0.2f * s;
    x = fminf(fmaxf(x, -2.0f), 2.0f);
    return __expf(x);
}

// ---------------- prep: W -> fragment-ordered bf16 WT | detect | wa ----------
// grid 66 x 256. blocks 0-63 convert W; block 64 detects edge dtype; 65 -> wa.
__global__ void __launch_bounds__(256) prep_kernel(const float* __restrict__ W,
                                                   const float* __restrict__ KA,
                                                   float* __restrict__ wa,
                                                   ushort_t* __restrict__ WT,
                                                   const int* __restrict__ E,
                                                   int* __restrict__ eflag) {
    __shared__ int s;
    int b = blockIdx.x, t = threadIdx.x;
    int i = b * 256 + t;
    if (b < 64) {                                   // fragment-order + bf16
        int k = i >> 7, nn = i & 127;
        int kb = k >> 5, q = (k >> 3) & 3, j = k & 7;
        int tt = nn >> 4, l = nn & 15;
        WT[((kb * 8 + tt) * 64 + q * 16 + l) * 8 + j] = f2bf(W[i]);
    } else if (b == 64) {                           // edge dtype detect
        if (t == 0) s = 0;
        __syncthreads();
        int nz = 0;
#pragma unroll
        for (int j = 0; j < 8; j++)
            if (E[(t + j * 256) * 2 + 1] != 0) nz = 1;
        if (nz) atomicOr(&s, 1);
        __syncthreads();
        if (t == 0) *eflag = (s == 0) ? 1 : 0;
    } else if (b == 65) {                           // wa = W @ ka (fp32 exact)
        int half = t >> 7, k = t & 127;
        const float* kav = KA + half * 128;
        const float* wrow = W + k * 128;
        float acc = 0.0f;
#pragma unroll 8
        for (int j = 0; j < 128; j++) acc += wrow[j] * kav[j];
        wa[half * 128 + k] = acc;
    }
}

// ---------------- mega1: [0..1562] MFMA gemm + fused score -------------------
//                  [1563..1812] B1: per-block bucket sort of edges (LDS only) -
__global__ void __launch_bounds__(256) mega1_kernel(const float* __restrict__ X,
                                                    const ushort_t* __restrict__ WT,
                                                    const float* __restrict__ wa,
                                                    ushort_t* __restrict__ H,
                                                    float* __restrict__ st,
                                                    float* __restrict__ ss,
                                                    int M,
                                                    const int* __restrict__ E,
                                                    const int* __restrict__ eflag,
                                                    int* __restrict__ sortedE,
                                                    int* __restrict__ bmatR,
                                                    int* __restrict__ lofsm) {
    // GEMM branch: per-wave output staging (ushort). B1 branch reuses as int[].
    __shared__ ushort_t ob[4][16 * 136];            // 17408 B
    if (blockIdx.x >= NB_GEMM) {
        // ------------- B1: bucket-sort 6400 edges by tgt>>7, LDS atomics only
        int eb = blockIdx.x - NB_GEMM;
        int t = threadIdx.x;
        int* lhist = (int*)ob;                      // [1024] (782 used)
        int* lpart = ((int*)ob) + 1024;             // [256]
        for (int j = t; j < 1024; j += 256) lhist[j] = 0;
        __syncthreads();
        int i64 = *eflag;                           // wave-uniform
        int base = eb * EPB;
        // pass 1: count buckets (25*256 = 6400 = EPB exactly)
        for (int j = 0; j < 25; j++) {
            int i = base + j * 256 + t;
            int tgt = i64 ? E[i * 4] : E[i * 2];
            if ((unsigned)tgt >= (unsigned)N_NODES) tgt = 0;
            atomicAdd(&lhist[tgt >> 7], 1);
        }
        __syncthreads();
        // per-thread 4 bins -> block scan
        int c0 = lhist[t * 4], c1 = lhist[t * 4 + 1];
        int c2 = lhist[t * 4 + 2], c3 = lhist[t * 4 + 3];
        int sum = c0 + c1 + c2 + c3;
        lpart[t] = sum;
        __syncthreads();
        for (int off = 1; off < 256; off <<= 1) {   // Hillis-Steele inclusive
            int x = (t >= off) ? lpart[t - off] : 0;
            __syncthreads();
            lpart[t] += x;
            __syncthreads();
        }
        int e0 = lpart[t] - sum;                    // exclusive base of bin 4t
        int e1 = e0 + c0, e2 = e1 + c1, e3 = e2 + c2;
        // write per-block histograms + local offsets (coalesced rows)
        int cc[4] = {c0, c1, c2, c3};
        int ee[4] = {e0, e1, e2, e3};
#pragma unroll
        for (int k = 0; k < 4; k++) {
            int bb = t * 4 + k;
            if (bb < BUCKETS) {
                bmatR[eb * BUCKETS + bb] = cc[k];
                lofsm[eb * BUCKETS + bb] = ee[k];
            }
        }
        // lhist becomes the placement cursor (own slots, no cross-thread reads)
        lhist[t * 4] = e0; lhist[t * 4 + 1] = e1;
        lhist[t * 4 + 2] = e2; lhist[t * 4 + 3] = e3;
        __syncthreads();
        // pass 2: place packed (tgt_local<<17)|src into block window
        for (int j = 0; j < 25; j++) {
            int i = base + j * 256 + t;
            int tgt, src;
            if (i64) { tgt = E[i * 4]; src = E[i * 4 + 2]; }
            else     { tgt = E[i * 2]; src = E[i * 2 + 1]; }
            if ((unsigned)tgt >= (unsigned)N_NODES) tgt = 0;
            if ((unsigned)src >= (unsigned)N_NODES) src = 0;
            int pos = atomicAdd(&lhist[tgt >> 7], 1);
            if (pos < EPB) sortedE[base + pos] = ((tgt & 127) << 17) | src;
        }
        return;
    }
    // ---------------- gemm + score branch (unchanged from r1) ---------------
    int tid = threadIdx.x;
    int wave = tid >> 6, lane = tid & 63;
    int quad = lane >> 4, l16 = lane & 15;
    int m0 = blockIdx.x * 64 + wave * 16;

    int arow = m0 + l16; if (arow >= M) arow = M - 1;   // clamp; stores guarded
    const float* xrow = X + (size_t)arow * D + quad * 8;
    short8 a[4];
    float sct = 0.0f, scs = 0.0f;             // fp32 score partials (exact path)
#pragma unroll
    for (int kb = 0; kb < 4; kb++) {          // A[m=l16][k=kb*32+quad*8+j]
        float4 f0 = *(const float4*)(xrow + kb * 32);
        float4 f1 = *(const float4*)(xrow + kb * 32 + 4);
        const float* wt0 = wa + kb * 32 + quad * 8;
        float4 t0 = *(const float4*)(wt0);
        float4 t1 = *(const float4*)(wt0 + 4);
        float4 s0 = *(const float4*)(wt0 + 128);
        float4 s1 = *(const float4*)(wt0 + 132);
        sct += f0.x * t0.x + f0.y * t0.y + f0.z * t0.z + f0.w * t0.w
             + f1.x * t1.x + f1.y * t1.y + f1.z * t1.z + f1.w * t1.w;
        scs += f0.x * s0.x + f0.y * s0.y + f0.z * s0.z + f0.w * s0.w
             + f1.x * s1.x + f1.y * s1.y + f1.z * s1.z + f1.w * s1.w;
        short8 v;
        v[0] = (short)f2bf(f0.x); v[1] = (short)f2bf(f0.y);
        v[2] = (short)f2bf(f0.z); v[3] = (short)f2bf(f0.w);
        v[4] = (short)f2bf(f1.x); v[5] = (short)f2bf(f1.y);
        v[6] = (short)f2bf(f1.z); v[7] = (short)f2bf(f1.w);
        a[kb] = v;
    }
    sct += __shfl_xor(sct, 16); sct += __shfl_xor(sct, 32);
    scs += __shfl_xor(scs, 16); scs += __shfl_xor(scs, 32);
    if (quad == 0 && m0 + l16 < M) { st[m0 + l16] = sct; ss[m0 + l16] = scs; }

    const short8* Bf = (const short8*)WT;     // 32 KB, L1/L2-resident
    float4v acc[8] = {};
#pragma unroll
    for (int kb = 0; kb < 4; kb++) {
#pragma unroll
        for (int t = 0; t < 8; t++) {         // B[k=kb*32+quad*8+j][n=t*16+l16]
            short8 b = Bf[(kb * 8 + t) * 64 + lane];
            acc[t] = __builtin_amdgcn_mfma_f32_16x16x32_bf16(a[kb], b, acc[t], 0, 0, 0);
        }
    }
    // C/D: col = lane&15, row = quad*4 + reg   [m89-verified]
    ushort_t* obw = ob[wave];
#pragma unroll
    for (int t = 0; t < 8; t++)
#pragma unroll
        for (int r = 0; r < 4; r++)
            obw[(quad * 4 + r) * 136 + t * 16 + l16] = f2bf(acc[t][r]);
    __syncthreads();                          // block-uniform in this branch
#pragma unroll
    for (int p = 0; p < 4; p++) {
        int row = p * 4 + quad;               // 4 rows/pass, 16 lanes/row
        int orow = m0 + row;
        if (orow < M) {
            uint4 v = *(const uint4*)(&obw[row * 136 + l16 * 8]);
            *(uint4*)(H + (size_t)orow * D + l16 * 8) = v;
        }
    }
}

// ---------------- S1: per-bucket exclusive scan across the 250 blocks --------
__global__ void __launch_bounds__(256) scanb_kernel(const int* __restrict__ bmatR,
                                                    int* __restrict__ offm,
                                                    int* __restrict__ bt) {
    __shared__ int l[256];
    int b = blockIdx.x, t = threadIdx.x;
    int v = (t < NB_B1) ? bmatR[t * BUCKETS + b] : 0;
    l[t] = v;
    __syncthreads();
    for (int off = 1; off < 256; off <<= 1) {
        int x = (t >= off) ? l[t - off] : 0;
        __syncthreads();
        l[t] += x;
        __syncthreads();
    }
    offm[b * 256 + t] = l[t] - v;             // staging offset within bucket
    if (t == 255) bt[b] = l[255];             // bucket total
}

// ---------------- S2: exclusive scan of 782 bucket totals --------------------
__global__ void __launch_bounds__(1024) scan2_kernel(const int* __restrict__ bt,
                                                     int* __restrict__ bbase,
                                                     int* __restrict__ rowp) {
    __shared__ int l[1024];
    int t = threadIdx.x;
    int v = (t < BUCKETS) ? bt[t] : 0;
    l[t] = v;
    __syncthreads();
    for (int off = 1; off < 1024; off <<= 1) {
        int x = (t >= off) ? l[t - off] : 0;
        __syncthreads();
        l[t] += x;
        __syncthreads();
    }
    if (t < BUCKETS) bbase[t] = l[t] - v;
    if (t == BUCKETS - 1) bbase[BUCKETS] = l[t];         // = N_EDGES
    if (t == 0) rowp[N_NODES] = N_EDGES;                 // sentinel
}

// ---------------- C: per-bucket CSR finalize (LDS hist+scan, no atomics) -----
__global__ void __launch_bounds__(256) csrb_kernel(const int* __restrict__ sortedE,
                                                   const int* __restrict__ bmatR,
                                                   const int* __restrict__ lofsm,
                                                   const int* __restrict__ offm,
                                                   const int* __restrict__ bbase,
                                                   int* __restrict__ rowp,
                                                   int* __restrict__ csr_src) {
    __shared__ int stage[4096];               // avg 2046, Poisson-safe cap
    __shared__ int lh[128];
    __shared__ int lsc[128];
    int b = blockIdx.x, t = threadIdx.x;
    int gbase = bbase[b];
    int total = bbase[b + 1] - gbase;
    if (total > 4096) total = 4096;           // statistically unreachable guard
    // gather: thread t pulls block t's segment for this bucket
    int soff = offm[b * 256 + t];
    int slen = 0, sstart = 0;
    if (t < NB_B1) {
        sstart = lofsm[t * BUCKETS + b];
        slen   = bmatR[t * BUCKETS + b];
    }
    for (int k = 0; k < slen; k++) {
        int idx = soff + k;
        if (idx < 4096) stage[idx] = sortedE[t * EPB + sstart + k];
    }
    if (t < 128) lh[t] = 0;
    __syncthreads();
    // LDS histogram over 128 local nodes
    for (int j = t; j < total; j += 256) atomicAdd(&lh[stage[j] >> 17], 1);
    __syncthreads();
    int v = (t < 128) ? lh[t] : 0;
    if (t < 128) lsc[t] = v;
    __syncthreads();
    for (int off = 1; off < 128; off <<= 1) {
        int x = (t >= off && t < 128) ? lsc[t - off] : 0;
        __syncthreads();
        if (t < 128) lsc[t] += x;
        __syncthreads();
    }
    if (t < 128) {
        int node = b * 128 + t;
        int ex = lsc[t] - v;
        if (node < N_NODES) rowp[node] = gbase + ex;
        lh[t] = ex;                           // becomes placement cursor
    }
    __syncthreads();
    // place: 8 KB window per block -> clean single-XCD L2 writebacks
    for (int j = t; j < total; j += 256) {
        int p = stage[j];
        int pos = atomicAdd(&lh[p >> 17], 1);
        if (pos < total) csr_src[gbase + pos] = p & 0x1FFFF;
    }
}

// ---------------- aggregation: 4 edges in flight per wave --------------------
__global__ void __launch_bounds__(256) agg_kernel(const int* __restrict__ rowp,
                                                  const int* __restrict__ csr_src,
                                                  const float* __restrict__ st,
                                                  const float* __restrict__ ss,
                                                  const ushort_t* __restrict__ H,
                                                  float* __restrict__ out, int n) {
    int wave = threadIdx.x >> 6, lane = threadIdx.x & 63;
    int node = blockIdx.x * 4 + wave;
    if (node >= n) return;
    node = __builtin_amdgcn_readfirstlane(node);  // scalarize rowp/st loads
    int g = lane >> 4, l = lane & 15;
    int start = rowp[node];
    int end   = rowp[node + 1];
    float stn = st[node];
    float den = 0.0f;
    float acc[8] = {};
    for (int m = start + g; m < end; m += 4) {
        int src = csr_src[m];                     // group-uniform
        float e = edge_e(stn + ss[src]);
        den += e;
        uint4 p = *(const uint4*)(H + (size_t)src * D + l * 8);  // 8 bf16
        acc[0] += e * bf2f(p.x & 0xffff); acc[1] += e * bf2f(p.x >> 16);
        acc[2] += e * bf2f(p.y & 0xffff); acc[3] += e * bf2f(p.y >> 16);
        acc[4] += e * bf2f(p.z & 0xffff); acc[5] += e * bf2f(p.z >> 16);
        acc[6] += e * bf2f(p.w & 0xffff); acc[7] += e * bf2f(p.w >> 16);
    }
    den += __shfl_xor(den, 16);
    den += __shfl_xor(den, 32);
#pragma unroll
    for (int j = 0; j < 8; j++) {
        acc[j] += __shfl_xor(acc[j], 16);
        acc[j] += __shfl_xor(acc[j], 32);
    }
    float inv = 1.0f / (den + 1e-9f);
    if (g == 0) {                                 // 16 lanes store 512B row
        float4 o0 = make_float4(acc[0] * inv, acc[1] * inv, acc[2] * inv, acc[3] * inv);
        float4 o1 = make_float4(acc[4] * inv, acc[5] * inv, acc[6] * inv, acc[7] * inv);
        *(float4*)(out + (size_t)node * D + l * 8) = o0;
        *(float4*)(out + (size_t)node * D + l * 8 + 4) = o1;
    }
}

extern "C" void kernel_launch(void* const* d_in, const int* in_sizes, int n_in,
                              void* d_out, int out_size, void* d_ws, size_t ws_size,
                              hipStream_t stream) {
    const float* X  = (const float*)d_in[0];
    const int*   E  = (const int*)d_in[1];
    const float* W  = (const float*)d_in[2];
    const float* KA = (const float*)d_in[3];
    for (int i = 0; i < n_in; i++) {
        int s = in_sizes[i];
        if (s == N_NODES * D)      X  = (const float*)d_in[i];
        else if (s == N_EDGES * 2) E  = (const int*)d_in[i];
        else if (s == D * D)       W  = (const float*)d_in[i];
        else if (s == 2 * D)       KA = (const float*)d_in[i];
    }
    float* out = (float*)d_out;                // fp32 [100000,128]
    // d_out head doubles as CSR-build scratch (consumed before agg writes out)
    char* ob = (char*)d_out;
    int* sortedE = (int*)(ob + 0);             // 6,400,000 B
    int* bmatR   = (int*)(ob + 6400000);       //   782,000 B (250*782 ints)
    int* lofsm   = (int*)(ob + 7200768);       //   782,000 B
    int* offm    = (int*)(ob + 8001536);       //   800,768 B (782*256 ints)
    int* bt      = (int*)(ob + 8802304);       //     3,128 B
    int* bbase   = (int*)(ob + 8805432);       //     3,132 B  (end ~8.81 MB)

    char* ws = (char*)d_ws;
    ushort_t* H        = (ushort_t*)(ws + 0);           // 25,600,000 B (bf16 h)
    float*    wa       = (float*)   (ws + 25600000);    //      1,024 B
    float*    st       = (float*)   (ws + 25601024);    //    400,000 B
    float*    ssb      = (float*)   (ws + 26001024);    //    400,000 B
    int*      rowp     = (int*)     (ws + 26801024);    //    400,016 B
    int*      csrs     = (int*)     (ws + 27201040);    //  6,400,000 B
    int*      eflag    = (int*)     (ws + 33601040);    //         16 B
    ushort_t* WT       = (ushort_t*)(ws + 33602656);    //     32,768 B

    const int NB_WAVE = (N_NODES + 3) / 4;              // 25000 (1 wave/node)

    prep_kernel<<<66, 256, 0, stream>>>(W, KA, wa, WT, E, eflag);
    mega1_kernel<<<NB_GEMM + NB_B1, 256, 0, stream>>>(X, WT, wa, H, st, ssb,
                                                      N_NODES, E, eflag,
                                                      sortedE, bmatR, lofsm);
    scanb_kernel<<<BUCKETS, 256, 0, stream>>>(bmatR, offm, bt);
    scan2_kernel<<<1, 1024, 0, stream>>>(bt, bbase, rowp);
    csrb_kernel<<<BUCKETS, 256, 0, stream>>>(sortedE, bmatR, lofsm, offm,
                                             bbase, rowp, csrs);
    agg_kernel<<<NB_WAVE, 256, 0, stream>>>(rowp, csrs, st, ssb, H, out, N_NODES);
}

// Round 5
// 235.692 us; speedup vs baseline: 1.2716x; 1.0224x over previous
//
#include <hip/hip_runtime.h>
#include <stdint.h>

typedef unsigned short ushort_t;
typedef __attribute__((ext_vector_type(8))) short short8;   // 8 bf16 = 4 VGPRs
typedef __attribute__((ext_vector_type(4))) float float4v;  // MFMA acc
typedef __attribute__((ext_vector_type(2))) float float2v;  // packed f32 pair

#define N_NODES 100000
#define N_EDGES 1600000
#define D 128
#define NB_GEMM 1563   // (N_NODES+63)/64 tiles of 64 rows
#define NBP     782    // persistent gemm blocks: tiles b and b+782
#define NB_B1   250    // edge-bucket blocks
#define EPB     6400   // edges per B1 block: 250*6400 = 1,600,000 = 25*256 each
#define BUCKETS 782    // ceil(100000/128), 128 nodes per bucket

static __device__ __forceinline__ float bf2f(uint32_t u) {
    return __builtin_bit_cast(float, u << 16);
}
static __device__ __forceinline__ float2v up2(uint32_t u) {  // 2 bf16 -> 2 f32
    float2v r;
    r.x = __builtin_bit_cast(float, u << 16);
    r.y = __builtin_bit_cast(float, u & 0xffff0000u);
    return r;
}
static __device__ __forceinline__ ushort_t f2bf(float f) {
    uint32_t u = __builtin_bit_cast(uint32_t, f);
    uint32_t r = u + 0x7fffu + ((u >> 16) & 1u);   // RNE
    return (ushort_t)(r >> 16);
}
// leaky_relu(0.2) -> clip(-2,2) -> exp
static __device__ __forceinline__ float edge_e(float s) {
    float x = (s >= 0.0f) ? s : 0.2f * s;
    x = fminf(fmaxf(x, -2.0f), 2.0f);
    return __expf(x);
}

// ---------------- prep: W -> fragment-ordered bf16 WT | detect | wa ----------
__global__ void __launch_bounds__(256) prep_kernel(const float* __restrict__ W,
                                                   const float* __restrict__ KA,
                                                   float* __restrict__ wa,
                                                   ushort_t* __restrict__ WT,
                                                   const int* __restrict__ E,
                                                   int* __restrict__ eflag) {
    __shared__ int s;
    int b = blockIdx.x, t = threadIdx.x;
    int i = b * 256 + t;
    if (b < 64) {                                   // fragment-order + bf16
        int k = i >> 7, nn = i & 127;
        int kb = k >> 5, q = (k >> 3) & 3, j = k & 7;
        int tt = nn >> 4, l = nn & 15;
        WT[((kb * 8 + tt) * 64 + q * 16 + l) * 8 + j] = f2bf(W[i]);
    } else if (b == 64) {                           // edge dtype detect
        if (t == 0) s = 0;
        __syncthreads();
        int nz = 0;
#pragma unroll
        for (int j = 0; j < 8; j++)
            if (E[(t + j * 256) * 2 + 1] != 0) nz = 1;
        if (nz) atomicOr(&s, 1);
        __syncthreads();
        if (t == 0) *eflag = (s == 0) ? 1 : 0;
    } else if (b == 65) {                           // wa = W @ ka (fp32 exact)
        int half = t >> 7, k = t & 127;
        const float* kav = KA + half * 128;
        const float* wrow = W + k * 128;
        float acc = 0.0f;
#pragma unroll 8
        for (int j = 0; j < 128; j++) acc += wrow[j] * kav[j];
        wa[half * 128 + k] = acc;
    }
}

// ---------------- mega1: [0..781] persistent MFMA gemm (2 tiles, prefetch) ---
//                  [782..1031] B1: per-block bucket sort of edges (LDS only) --
__global__ void __launch_bounds__(256) mega1_kernel(const float* __restrict__ X,
                                                    const ushort_t* __restrict__ WT,
                                                    const float* __restrict__ wa,
                                                    ushort_t* __restrict__ H,
                                                    float* __restrict__ st,
                                                    float* __restrict__ ss,
                                                    int M,
                                                    const int* __restrict__ E,
                                                    const int* __restrict__ eflag,
                                                    int* __restrict__ sortedE,
                                                    int* __restrict__ bmatR,
                                                    int* __restrict__ lofsm) {
    // GEMM branch: per-wave output staging (ushort). B1 branch reuses as int[].
    __shared__ ushort_t ob[4][16 * 136];            // 17408 B
    if (blockIdx.x >= NBP) {
        // ------------- B1: bucket-sort 6400 edges by tgt>>7, LDS atomics only
        int eb = blockIdx.x - NBP;
        int t = threadIdx.x;
        int* lhist = (int*)ob;                      // [1024] (782 used)
        int* lpart = ((int*)ob) + 1024;             // [256]
        for (int j = t; j < 1024; j += 256) lhist[j] = 0;
        __syncthreads();
        int i64 = *eflag;                           // wave-uniform
        int base = eb * EPB;
        // pass 1: count buckets (25*256 = 6400 = EPB exactly)
        for (int j = 0; j < 25; j++) {
            int i = base + j * 256 + t;
            int tgt = i64 ? E[i * 4] : E[i * 2];
            if ((unsigned)tgt >= (unsigned)N_NODES) tgt = 0;
            atomicAdd(&lhist[tgt >> 7], 1);
        }
        __syncthreads();
        // per-thread 4 bins -> block scan
        int c0 = lhist[t * 4], c1 = lhist[t * 4 + 1];
        int c2 = lhist[t * 4 + 2], c3 = lhist[t * 4 + 3];
        int sum = c0 + c1 + c2 + c3;
        lpart[t] = sum;
        __syncthreads();
        for (int off = 1; off < 256; off <<= 1) {   // Hillis-Steele inclusive
            int x = (t >= off) ? lpart[t - off] : 0;
            __syncthreads();
            lpart[t] += x;
            __syncthreads();
        }
        int e0 = lpart[t] - sum;                    // exclusive base of bin 4t
        int e1 = e0 + c0, e2 = e1 + c1, e3 = e2 + c2;
        int cc[4] = {c0, c1, c2, c3};
        int ee[4] = {e0, e1, e2, e3};
#pragma unroll
        for (int k = 0; k < 4; k++) {
            int bb = t * 4 + k;
            if (bb < BUCKETS) {
                bmatR[eb * BUCKETS + bb] = cc[k];
                lofsm[eb * BUCKETS + bb] = ee[k];
            }
        }
        // lhist becomes the placement cursor (own slots, no cross-thread reads)
        lhist[t * 4] = e0; lhist[t * 4 + 1] = e1;
        lhist[t * 4 + 2] = e2; lhist[t * 4 + 3] = e3;
        __syncthreads();
        // pass 2: place packed (tgt_local<<17)|src into block window
        for (int j = 0; j < 25; j++) {
            int i = base + j * 256 + t;
            int tgt, src;
            if (i64) { tgt = E[i * 4]; src = E[i * 4 + 2]; }
            else     { tgt = E[i * 2]; src = E[i * 2 + 1]; }
            if ((unsigned)tgt >= (unsigned)N_NODES) tgt = 0;
            if ((unsigned)src >= (unsigned)N_NODES) src = 0;
            int pos = atomicAdd(&lhist[tgt >> 7], 1);
            if (pos < EPB) sortedE[base + pos] = ((tgt & 127) << 17) | src;
        }
        return;
    }
    // -------- gemm branch: 2 tiles per block, next-tile X prefetched --------
    int tid = threadIdx.x;
    int wave = tid >> 6, lane = tid & 63;
    int quad = lane >> 4, l16 = lane & 15;
    ushort_t* obw = ob[wave];                 // wave-private: no barriers needed
    const short8* Bf = (const short8*)WT;     // 32 KB, L1/L2-resident

    int t0 = blockIdx.x;
    int nt = (t0 + NBP < NB_GEMM) ? 2 : 1;

    float4 f[8];                              // current tile X (A rows)
    {
        int ar = t0 * 64 + wave * 16 + l16; if (ar >= M) ar = M - 1;
        const float* xr = X + (size_t)ar * D + quad * 8;
#pragma unroll
        for (int kb = 0; kb < 4; kb++) {
            f[kb * 2]     = *(const float4*)(xr + kb * 32);
            f[kb * 2 + 1] = *(const float4*)(xr + kb * 32 + 4);
        }
    }
    for (int it = 0; it < nt; it++) {
        int m0 = (t0 + it * NBP) * 64 + wave * 16;
        float4 nf[8];
        if (it + 1 < nt) {                    // prefetch next tile's X now
            int ar = (t0 + NBP) * 64 + wave * 16 + l16; if (ar >= M) ar = M - 1;
            const float* xr = X + (size_t)ar * D + quad * 8;
#pragma unroll
            for (int kb = 0; kb < 4; kb++) {
                nf[kb * 2]     = *(const float4*)(xr + kb * 32);
                nf[kb * 2 + 1] = *(const float4*)(xr + kb * 32 + 4);
            }
        }
        // fused scores (fp32 exact) + bf16 cvt
        short8 a[4];
        float sct = 0.0f, scs = 0.0f;
#pragma unroll
        for (int kb = 0; kb < 4; kb++) {      // A[m=l16][k=kb*32+quad*8+j]
            float4 f0 = f[kb * 2], f1 = f[kb * 2 + 1];
            const float* wt0 = wa + kb * 32 + quad * 8;
            float4 t0v = *(const float4*)(wt0);
            float4 t1v = *(const float4*)(wt0 + 4);
            float4 s0v = *(const float4*)(wt0 + 128);
            float4 s1v = *(const float4*)(wt0 + 132);
            sct += f0.x * t0v.x + f0.y * t0v.y + f0.z * t0v.z + f0.w * t0v.w
                 + f1.x * t1v.x + f1.y * t1v.y + f1.z * t1v.z + f1.w * t1v.w;
            scs += f0.x * s0v.x + f0.y * s0v.y + f0.z * s0v.z + f0.w * s0v.w
                 + f1.x * s1v.x + f1.y * s1v.y + f1.z * s1v.z + f1.w * s1v.w;
            short8 v;
            v[0] = (short)f2bf(f0.x); v[1] = (short)f2bf(f0.y);
            v[2] = (short)f2bf(f0.z); v[3] = (short)f2bf(f0.w);
            v[4] = (short)f2bf(f1.x); v[5] = (short)f2bf(f1.y);
            v[6] = (short)f2bf(f1.z); v[7] = (short)f2bf(f1.w);
            a[kb] = v;
        }
        sct += __shfl_xor(sct, 16); sct += __shfl_xor(sct, 32);
        scs += __shfl_xor(scs, 16); scs += __shfl_xor(scs, 32);
        if (quad == 0 && m0 + l16 < M) { st[m0 + l16] = sct; ss[m0 + l16] = scs; }

        float4v acc[8] = {};
#pragma unroll
        for (int kb = 0; kb < 4; kb++) {
#pragma unroll
            for (int t = 0; t < 8; t++) {     // B[k=kb*32+quad*8+j][n=t*16+l16]
                short8 b = Bf[(kb * 8 + t) * 64 + lane];
                acc[t] = __builtin_amdgcn_mfma_f32_16x16x32_bf16(a[kb], b, acc[t], 0, 0, 0);
            }
        }
        // C/D: col = lane&15, row = quad*4 + reg   [m89-verified]
        // stage to wave-private LDS, then coalesced 16B stores (no barrier)
#pragma unroll
        for (int t = 0; t < 8; t++)
#pragma unroll
            for (int r = 0; r < 4; r++)
                obw[(quad * 4 + r) * 136 + t * 16 + l16] = f2bf(acc[t][r]);
#pragma unroll
        for (int p = 0; p < 4; p++) {
            int row = p * 4 + quad;           // 4 rows/pass, 16 lanes/row
            int orow = m0 + row;
            if (orow < M) {
                uint4 v = *(const uint4*)(&obw[row * 136 + l16 * 8]);
                *(uint4*)(H + (size_t)orow * D + l16 * 8) = v;
            }
        }
        if (it + 1 < nt) {
#pragma unroll
            for (int j = 0; j < 8; j++) f[j] = nf[j];
        }
    }
}

// ---------------- S1: per-bucket exclusive scan across the 250 blocks --------
__global__ void __launch_bounds__(256) scanb_kernel(const int* __restrict__ bmatR,
                                                    int* __restrict__ offm,
                                                    int* __restrict__ bt) {
    __shared__ int l[256];
    int b = blockIdx.x, t = threadIdx.x;
    int v = (t < NB_B1) ? bmatR[t * BUCKETS + b] : 0;
    l[t] = v;
    __syncthreads();
    for (int off = 1; off < 256; off <<= 1) {
        int x = (t >= off) ? l[t - off] : 0;
        __syncthreads();
        l[t] += x;
        __syncthreads();
    }
    offm[b * 256 + t] = l[t] - v;             // staging offset within bucket
    if (t == 255) bt[b] = l[255];             // bucket total
}

// ---------------- S2: exclusive scan of 782 bucket totals --------------------
__global__ void __launch_bounds__(1024) scan2_kernel(const int* __restrict__ bt,
                                                     int* __restrict__ bbase,
                                                     int* __restrict__ rowp) {
    __shared__ int l[1024];
    int t = threadIdx.x;
    int v = (t < BUCKETS) ? bt[t] : 0;
    l[t] = v;
    __syncthreads();
    for (int off = 1; off < 1024; off <<= 1) {
        int x = (t >= off) ? l[t - off] : 0;
        __syncthreads();
        l[t] += x;
        __syncthreads();
    }
    if (t < BUCKETS) bbase[t] = l[t] - v;
    if (t == BUCKETS - 1) bbase[BUCKETS] = l[t];         // = N_EDGES
    if (t == 0) rowp[N_NODES] = N_EDGES;                 // sentinel
}

// ---------------- C: per-bucket CSR finalize (LDS hist+scan) -----------------
__global__ void __launch_bounds__(256) csrb_kernel(const int* __restrict__ sortedE,
                                                   const int* __restrict__ bmatR,
                                                   const int* __restrict__ lofsm,
                                                   const int* __restrict__ offm,
                                                   const int* __restrict__ bbase,
                                                   int* __restrict__ rowp,
                                                   int* __restrict__ csr_src) {
    __shared__ int stage[4096];               // avg 2046, Poisson-safe cap
    __shared__ int lh[128];
    __shared__ int lsc[128];
    int b = blockIdx.x, t = threadIdx.x;
    int gbase = bbase[b];
    int total = bbase[b + 1] - gbase;
    if (total > 4096) total = 4096;           // statistically unreachable guard
    // gather: thread t pulls block t's segment for this bucket
    int soff = offm[b * 256 + t];
    int slen = 0, sstart = 0;
    if (t < NB_B1) {
        sstart = lofsm[t * BUCKETS + b];
        slen   = bmatR[t * BUCKETS + b];
    }
    for (int k = 0; k < slen; k++) {
        int idx = soff + k;
        if (idx < 4096) stage[idx] = sortedE[t * EPB + sstart + k];
    }
    if (t < 128) lh[t] = 0;
    __syncthreads();
    // LDS histogram over 128 local nodes
    for (int j = t; j < total; j += 256) atomicAdd(&lh[stage[j] >> 17], 1);
    __syncthreads();
    int v = (t < 128) ? lh[t] : 0;
    if (t < 128) lsc[t] = v;
    __syncthreads();
    for (int off = 1; off < 128; off <<= 1) {
        int x = (t >= off && t < 128) ? lsc[t - off] : 0;
        __syncthreads();
        if (t < 128) lsc[t] += x;
        __syncthreads();
    }
    if (t < 128) {
        int node = b * 128 + t;
        int ex = lsc[t] - v;
        if (node < N_NODES) rowp[node] = gbase + ex;
        lh[t] = ex;                           // becomes placement cursor
    }
    __syncthreads();
    // place: 8 KB window per block -> clean single-XCD L2 writebacks
    for (int j = t; j < total; j += 256) {
        int p = stage[j];
        int pos = atomicAdd(&lh[p >> 17], 1);
        if (pos < total) csr_src[gbase + pos] = p & 0x1FFFF;
    }
}

// ---------------- aggregation: 8 edges in flight per wave, packed FMA --------
__global__ void __launch_bounds__(256) agg_kernel(const int* __restrict__ rowp,
                                                  const int* __restrict__ csr_src,
                                                  const float* __restrict__ st,
                                                  const float* __restrict__ ss,
                                                  const ushort_t* __restrict__ H,
                                                  float* __restrict__ out, int n) {
    int wave = threadIdx.x >> 6, lane = threadIdx.x & 63;
    int node = blockIdx.x * 4 + wave;
    if (node >= n) return;
    node = __builtin_amdgcn_readfirstlane(node);  // scalarize rowp/st loads
    int g = lane >> 4, l = lane & 15;
    int start = rowp[node];
    int end   = rowp[node + 1];
    float stn = st[node];
    float den = 0.0f;
    float2v acc2[4] = {};                     // 8 cols as 4 packed pairs
    int m = start + g;
    // unroll-2: two independent csr->H load chains in flight per group
    for (; m + 4 < end; m += 8) {
        int s0 = csr_src[m], s1 = csr_src[m + 4];     // group-uniform
        float e0 = edge_e(stn + ss[s0]);
        float e1 = edge_e(stn + ss[s1]);
        den += e0 + e1;
        uint4 p0 = *(const uint4*)(H + ((unsigned)s0 << 7) + l * 8);
        uint4 p1 = *(const uint4*)(H + ((unsigned)s1 << 7) + l * 8);
        float2v E0 = {e0, e0}, E1 = {e1, e1};
        acc2[0] += E0 * up2(p0.x) + E1 * up2(p1.x);
        acc2[1] += E0 * up2(p0.y) + E1 * up2(p1.y);
        acc2[2] += E0 * up2(p0.z) + E1 * up2(p1.z);
        acc2[3] += E0 * up2(p0.w) + E1 * up2(p1.w);
    }
    if (m < end) {
        int s0 = csr_src[m];
        float e0 = edge_e(stn + ss[s0]);
        den += e0;
        uint4 p0 = *(const uint4*)(H + ((unsigned)s0 << 7) + l * 8);
        float2v E0 = {e0, e0};
        acc2[0] += E0 * up2(p0.x);
        acc2[1] += E0 * up2(p0.y);
        acc2[2] += E0 * up2(p0.z);
        acc2[3] += E0 * up2(p0.w);
    }
    den += __shfl_xor(den, 16);
    den += __shfl_xor(den, 32);
    float r[8];
#pragma unroll
    for (int j = 0; j < 4; j++) {
        float a0 = acc2[j].x, a1 = acc2[j].y;
        a0 += __shfl_xor(a0, 16); a0 += __shfl_xor(a0, 32);
        a1 += __shfl_xor(a1, 16); a1 += __shfl_xor(a1, 32);
        r[j * 2] = a0; r[j * 2 + 1] = a1;
    }
    float inv = 1.0f / (den + 1e-9f);
    if (g == 0) {                                 // 16 lanes store 512B row
        float4 o0 = make_float4(r[0] * inv, r[1] * inv, r[2] * inv, r[3] * inv);
        float4 o1 = make_float4(r[4] * inv, r[5] * inv, r[6] * inv, r[7] * inv);
        *(float4*)(out + (size_t)node * D + l * 8) = o0;
        *(float4*)(out + (size_t)node * D + l * 8 + 4) = o1;
    }
}

extern "C" void kernel_launch(void* const* d_in, const int* in_sizes, int n_in,
                              void* d_out, int out_size, void* d_ws, size_t ws_size,
                              hipStream_t stream) {
    const float* X  = (const float*)d_in[0];
    const int*   E  = (const int*)d_in[1];
    const float* W  = (const float*)d_in[2];
    const float* KA = (const float*)d_in[3];
    for (int i = 0; i < n_in; i++) {
        int s = in_sizes[i];
        if (s == N_NODES * D)      X  = (const float*)d_in[i];
        else if (s == N_EDGES * 2) E  = (const int*)d_in[i];
        else if (s == D * D)       W  = (const float*)d_in[i];
        else if (s == 2 * D)       KA = (const float*)d_in[i];
    }
    float* out = (float*)d_out;                // fp32 [100000,128]
    // d_out head doubles as CSR-build scratch (consumed before agg writes out)
    char* ob = (char*)d_out;
    int* sortedE = (int*)(ob + 0);             // 6,400,000 B
    int* bmatR   = (int*)(ob + 6400000);       //   782,000 B (250*782 ints)
    int* lofsm   = (int*)(ob + 7200768);       //   782,000 B
    int* offm    = (int*)(ob + 8001536);       //   800,768 B (782*256 ints)
    int* bt      = (int*)(ob + 8802304);       //     3,128 B
    int* bbase   = (int*)(ob + 8805432);       //     3,132 B  (end ~8.81 MB)

    char* ws = (char*)d_ws;
    ushort_t* H        = (ushort_t*)(ws + 0);           // 25,600,000 B (bf16 h)
    float*    wa       = (float*)   (ws + 25600000);    //      1,024 B
    float*    st       = (float*)   (ws + 25601024);    //    400,000 B
    float*    ssb      = (float*)   (ws + 26001024);    //    400,000 B
    int*      rowp     = (int*)     (ws + 26801024);    //    400,016 B
    int*      csrs     = (int*)     (ws + 27201040);    //  6,400,000 B
    int*      eflag    = (int*)     (ws + 33601040);    //         16 B
    ushort_t* WT       = (ushort_t*)(ws + 33602656);    //     32,768 B

    const int NB_WAVE = (N_NODES + 3) / 4;              // 25000 (1 wave/node)

    prep_kernel<<<66, 256, 0, stream>>>(W, KA, wa, WT, E, eflag);
    mega1_kernel<<<NBP + NB_B1, 256, 0, stream>>>(X, WT, wa, H, st, ssb,
                                                  N_NODES, E, eflag,
                                                  sortedE, bmatR, lofsm);
    scanb_kernel<<<BUCKETS, 256, 0, stream>>>(bmatR, offm, bt);
    scan2_kernel<<<1, 1024, 0, stream>>>(bt, bbase, rowp);
    csrb_kernel<<<BUCKETS, 256, 0, stream>>>(sortedE, bmatR, lofsm, offm,
                                             bbase, rowp, csrs);
    agg_kernel<<<NB_WAVE, 256, 0, stream>>>(rowp, csrs, st, ssb, H, out, N_NODES);
}

// Round 6
// 229.853 us; speedup vs baseline: 1.3039x; 1.0254x over previous
//
#include <hip/hip_runtime.h>
#include <stdint.h>

typedef unsigned short ushort_t;
typedef __attribute__((ext_vector_type(8))) short short8;   // 8 bf16 = 4 VGPRs
typedef __attribute__((ext_vector_type(4))) float float4v;  // MFMA acc
typedef __attribute__((ext_vector_type(2))) float float2v;  // packed f32 pair

#define N_NODES 100000
#define N_EDGES 1600000
#define D 128
#define NB_GEMM 1563   // (N_NODES+63)/64 tiles of 64 rows
#define NBP     782    // persistent gemm blocks: tiles b and b+782
#define NB_B1   250    // edge-bucket blocks
#define EPB     6400   // edges per B1 block: 250*6400 = 1,600,000 = 25*256 each
#define BUCKETS 782    // ceil(100000/128), 128 nodes per bucket
#define CAP     2560   // per-bucket edge capacity (mean 2046, sd 45 -> 11 sigma)

static __device__ __forceinline__ float2v up2(uint32_t u) {  // 2 bf16 -> 2 f32
    float2v r;
    r.x = __builtin_bit_cast(float, u << 16);
    r.y = __builtin_bit_cast(float, u & 0xffff0000u);
    return r;
}
static __device__ __forceinline__ ushort_t f2bf(float f) {
    uint32_t u = __builtin_bit_cast(uint32_t, f);
    uint32_t r = u + 0x7fffu + ((u >> 16) & 1u);   // RNE
    return (ushort_t)(r >> 16);
}
// leaky_relu(0.2) -> clip(-2,2) -> exp
static __device__ __forceinline__ float edge_e(float s) {
    float x = (s >= 0.0f) ? s : 0.2f * s;
    x = fminf(fmaxf(x, -2.0f), 2.0f);
    return __expf(x);
}

// ---------------- prep: W -> fragment-ordered bf16 WT | detect | wa ----------
__global__ void __launch_bounds__(256) prep_kernel(const float* __restrict__ W,
                                                   const float* __restrict__ KA,
                                                   float* __restrict__ wa,
                                                   ushort_t* __restrict__ WT,
                                                   const int* __restrict__ E,
                                                   int* __restrict__ eflag) {
    __shared__ int s;
    int b = blockIdx.x, t = threadIdx.x;
    int i = b * 256 + t;
    if (b < 64) {                                   // fragment-order + bf16
        int k = i >> 7, nn = i & 127;
        int kb = k >> 5, q = (k >> 3) & 3, j = k & 7;
        int tt = nn >> 4, l = nn & 15;
        WT[((kb * 8 + tt) * 64 + q * 16 + l) * 8 + j] = f2bf(W[i]);
    } else if (b == 64) {                           // edge dtype detect
        if (t == 0) s = 0;
        __syncthreads();
        int nz = 0;
#pragma unroll
        for (int j = 0; j < 8; j++)
            if (E[(t + j * 256) * 2 + 1] != 0) nz = 1;
        if (nz) atomicOr(&s, 1);
        __syncthreads();
        if (t == 0) *eflag = (s == 0) ? 1 : 0;
    } else if (b == 65) {                           // wa = W @ ka (fp32 exact)
        int half = t >> 7, k = t & 127;
        const float* kav = KA + half * 128;
        const float* wrow = W + k * 128;
        float acc = 0.0f;
#pragma unroll 8
        for (int j = 0; j < 128; j++) acc += wrow[j] * kav[j];
        wa[half * 128 + k] = acc;
    }
}

// ---------------- mega1: [0..781] persistent MFMA gemm (2 tiles, prefetch) ---
//                  [782..1031] B1: per-block bucket sort of edges (LDS only) --
__global__ void __launch_bounds__(256) mega1_kernel(const float* __restrict__ X,
                                                    const ushort_t* __restrict__ WT,
                                                    const float* __restrict__ wa,
                                                    ushort_t* __restrict__ H,
                                                    float* __restrict__ st,
                                                    float* __restrict__ ss,
                                                    int M,
                                                    const int* __restrict__ E,
                                                    const int* __restrict__ eflag,
                                                    int* __restrict__ sortedE,
                                                    ushort_t* __restrict__ bmat,
                                                    ushort_t* __restrict__ lofs) {
    // GEMM branch: per-wave output staging (ushort). B1 branch reuses as int[].
    __shared__ ushort_t ob[4][16 * 136];            // 17408 B
    if (blockIdx.x >= NBP) {
        // ------------- B1: bucket-sort 6400 edges by tgt>>7, LDS atomics only
        int eb = blockIdx.x - NBP;
        int t = threadIdx.x;
        int* lhist = (int*)ob;                      // [1024] (782 used)
        int* lpart = ((int*)ob) + 1024;             // [256]
        for (int j = t; j < 1024; j += 256) lhist[j] = 0;
        __syncthreads();
        int i64 = *eflag;                           // wave-uniform
        int base = eb * EPB;
        // pass 1: count buckets (25*256 = 6400 = EPB exactly)
        for (int j = 0; j < 25; j++) {
            int i = base + j * 256 + t;
            int tgt = i64 ? E[i * 4] : E[i * 2];
            if ((unsigned)tgt >= (unsigned)N_NODES) tgt = 0;
            atomicAdd(&lhist[tgt >> 7], 1);
        }
        __syncthreads();
        // per-thread 4 bins -> block scan
        int c0 = lhist[t * 4], c1 = lhist[t * 4 + 1];
        int c2 = lhist[t * 4 + 2], c3 = lhist[t * 4 + 3];
        int sum = c0 + c1 + c2 + c3;
        lpart[t] = sum;
        __syncthreads();
        for (int off = 1; off < 256; off <<= 1) {   // Hillis-Steele inclusive
            int x = (t >= off) ? lpart[t - off] : 0;
            __syncthreads();
            lpart[t] += x;
            __syncthreads();
        }
        int e0 = lpart[t] - sum;                    // exclusive base of bin 4t
        int e1 = e0 + c0, e2 = e1 + c1, e3 = e2 + c2;
        int cc[4] = {c0, c1, c2, c3};
        int ee[4] = {e0, e1, e2, e3};
#pragma unroll
        for (int k = 0; k < 4; k++) {
            int bb = t * 4 + k;
            if (bb < BUCKETS) {
                bmat[eb * BUCKETS + bb] = (ushort_t)cc[k];
                lofs[eb * BUCKETS + bb] = (ushort_t)ee[k];
            }
        }
        // lhist becomes the placement cursor (own slots, no cross-thread reads)
        lhist[t * 4] = e0; lhist[t * 4 + 1] = e1;
        lhist[t * 4 + 2] = e2; lhist[t * 4 + 3] = e3;
        __syncthreads();
        // pass 2: place packed (tgt_local<<17)|src into block window
        for (int j = 0; j < 25; j++) {
            int i = base + j * 256 + t;
            int tgt, src;
            if (i64) { tgt = E[i * 4]; src = E[i * 4 + 2]; }
            else     { tgt = E[i * 2]; src = E[i * 2 + 1]; }
            if ((unsigned)tgt >= (unsigned)N_NODES) tgt = 0;
            if ((unsigned)src >= (unsigned)N_NODES) src = 0;
            int pos = atomicAdd(&lhist[tgt >> 7], 1);
            if (pos < EPB) sortedE[base + pos] = ((tgt & 127) << 17) | src;
        }
        return;
    }
    // -------- gemm branch: 2 tiles per block, next-tile X prefetched --------
    int tid = threadIdx.x;
    int wave = tid >> 6, lane = tid & 63;
    int quad = lane >> 4, l16 = lane & 15;
    ushort_t* obw = ob[wave];                 // wave-private: no barriers needed
    const short8* Bf = (const short8*)WT;     // 32 KB, L1/L2-resident

    int t0 = blockIdx.x;
    int nt = (t0 + NBP < NB_GEMM) ? 2 : 1;

    float4 f[8];                              // current tile X (A rows)
    {
        int ar = t0 * 64 + wave * 16 + l16; if (ar >= M) ar = M - 1;
        const float* xr = X + (size_t)ar * D + quad * 8;
#pragma unroll
        for (int kb = 0; kb < 4; kb++) {
            f[kb * 2]     = *(const float4*)(xr + kb * 32);
            f[kb * 2 + 1] = *(const float4*)(xr + kb * 32 + 4);
        }
    }
    for (int it = 0; it < nt; it++) {
        int m0 = (t0 + it * NBP) * 64 + wave * 16;
        float4 nf[8];
        if (it + 1 < nt) {                    // prefetch next tile's X now
            int ar = (t0 + NBP) * 64 + wave * 16 + l16; if (ar >= M) ar = M - 1;
            const float* xr = X + (size_t)ar * D + quad * 8;
#pragma unroll
            for (int kb = 0; kb < 4; kb++) {
                nf[kb * 2]     = *(const float4*)(xr + kb * 32);
                nf[kb * 2 + 1] = *(const float4*)(xr + kb * 32 + 4);
            }
        }
        // fused scores (fp32 exact) + bf16 cvt
        short8 a[4];
        float sct = 0.0f, scs = 0.0f;
#pragma unroll
        for (int kb = 0; kb < 4; kb++) {      // A[m=l16][k=kb*32+quad*8+j]
            float4 f0 = f[kb * 2], f1 = f[kb * 2 + 1];
            const float* wt0 = wa + kb * 32 + quad * 8;
            float4 t0v = *(const float4*)(wt0);
            float4 t1v = *(const float4*)(wt0 + 4);
            float4 s0v = *(const float4*)(wt0 + 128);
            float4 s1v = *(const float4*)(wt0 + 132);
            sct += f0.x * t0v.x + f0.y * t0v.y + f0.z * t0v.z + f0.w * t0v.w
                 + f1.x * t1v.x + f1.y * t1v.y + f1.z * t1v.z + f1.w * t1v.w;
            scs += f0.x * s0v.x + f0.y * s0v.y + f0.z * s0v.z + f0.w * s0v.w
                 + f1.x * s1v.x + f1.y * s1v.y + f1.z * s1v.z + f1.w * s1v.w;
            short8 v;
            v[0] = (short)f2bf(f0.x); v[1] = (short)f2bf(f0.y);
            v[2] = (short)f2bf(f0.z); v[3] = (short)f2bf(f0.w);
            v[4] = (short)f2bf(f1.x); v[5] = (short)f2bf(f1.y);
            v[6] = (short)f2bf(f1.z); v[7] = (short)f2bf(f1.w);
            a[kb] = v;
        }
        sct += __shfl_xor(sct, 16); sct += __shfl_xor(sct, 32);
        scs += __shfl_xor(scs, 16); scs += __shfl_xor(scs, 32);
        if (quad == 0 && m0 + l16 < M) { st[m0 + l16] = sct; ss[m0 + l16] = scs; }

        float4v acc[8] = {};
#pragma unroll
        for (int kb = 0; kb < 4; kb++) {
#pragma unroll
            for (int t = 0; t < 8; t++) {     // B[k=kb*32+quad*8+j][n=t*16+l16]
                short8 b = Bf[(kb * 8 + t) * 64 + lane];
                acc[t] = __builtin_amdgcn_mfma_f32_16x16x32_bf16(a[kb], b, acc[t], 0, 0, 0);
            }
        }
        // C/D: col = lane&15, row = quad*4 + reg   [m89-verified]
        // stage to wave-private LDS, then coalesced 16B stores (no barrier)
#pragma unroll
        for (int t = 0; t < 8; t++)
#pragma unroll
            for (int r = 0; r < 4; r++)
                obw[(quad * 4 + r) * 136 + t * 16 + l16] = f2bf(acc[t][r]);
#pragma unroll
        for (int p = 0; p < 4; p++) {
            int row = p * 4 + quad;           // 4 rows/pass, 16 lanes/row
            int orow = m0 + row;
            if (orow < M) {
                uint4 v = *(const uint4*)(&obw[row * 136 + l16 * 8]);
                *(uint4*)(H + (size_t)orow * D + l16 * 8) = v;
            }
        }
        if (it + 1 < nt) {
#pragma unroll
            for (int j = 0; j < 8; j++) f[j] = nf[j];
        }
    }
}

// ---------------- agg2: fused CSR-build + aggregation, 1 block = 1 bucket ----
// Phase A: scan 250 window-counts, gather edges to LDS, hist+scan+place sort.
// Phase B: 8 waves x 16 nodes, 4 edge-slot groups/wave, unroll-2 gather of H.
__global__ void __launch_bounds__(512) agg2_kernel(const ushort_t* __restrict__ bmat,
                                                   const ushort_t* __restrict__ lofs,
                                                   const int* __restrict__ sortedE,
                                                   const float* __restrict__ st,
                                                   const float* __restrict__ ss,
                                                   const ushort_t* __restrict__ H,
                                                   float* __restrict__ out) {
    __shared__ int stage[CAP];
    __shared__ int sortedLoc[CAP];
    __shared__ int lpart[512];
    __shared__ int lh[128];
    __shared__ int lrp[129];
    int b = blockIdx.x, t = threadIdx.x;
    // segment (count, start) for window t of this bucket
    int cnt = 0, sst = 0;
    if (t < NB_B1) {
        cnt = bmat[t * BUCKETS + b];
        sst = lofs[t * BUCKETS + b];
    }
    lpart[t] = cnt;
    __syncthreads();
    for (int off = 1; off < 512; off <<= 1) {       // Hillis-Steele inclusive
        int x = (t >= off) ? lpart[t - off] : 0;
        __syncthreads();
        lpart[t] += x;
        __syncthreads();
    }
    int soff  = lpart[t] - cnt;                     // staging offset
    int total = lpart[511];
    if (total > CAP) total = CAP;                   // 11-sigma guard
    if (t < 128) lh[t] = 0;
    for (int k = 0; k < cnt; k++) {                 // gather my segment
        int idx = soff + k;
        if (idx < CAP) stage[idx] = sortedE[t * EPB + sst + k];
    }
    __syncthreads();
    for (int j = t; j < total; j += 512)            // hist over 128 local nodes
        atomicAdd(&lh[stage[j] >> 17], 1);
    __syncthreads();
    int v = (t < 128) ? lh[t] : 0;                  // scan hist -> local rowp
    if (t < 128) lpart[t] = v;
    __syncthreads();
    for (int off = 1; off < 128; off <<= 1) {
        int x = (t >= off && t < 128) ? lpart[t - off] : 0;
        __syncthreads();
        if (t < 128) lpart[t] += x;
        __syncthreads();
    }
    if (t < 128) {
        int ex = lpart[t] - v;
        lrp[t] = ex;
        lh[t]  = ex;                                // placement cursor
    }
    if (t == 0) lrp[128] = total;
    __syncthreads();
    for (int j = t; j < total; j += 512) {          // place sorted-by-node
        int p = stage[j];
        int pos = atomicAdd(&lh[p >> 17], 1);
        if (pos < total) sortedLoc[pos] = p & 0x1FFFF;
    }
    __syncthreads();
    // ---------------- Phase B: aggregate from LDS-sorted edges --------------
    int wave = t >> 6, lane = t & 63;
    int g = lane >> 4, l = lane & 15;
    for (int nd = wave; nd < 128; nd += 8) {
        int gnode = b * 128 + nd;
        if (gnode >= N_NODES) break;                // only bucket 781 tail
        int start = lrp[nd], end = lrp[nd + 1];
        float stn = st[gnode];
        float den = 0.0f;
        float2v acc2[4] = {};
        int m = start + g;
        for (; m + 4 < end; m += 8) {               // 2 chains in flight/group
            int s0 = sortedLoc[m], s1 = sortedLoc[m + 4];
            float e0 = edge_e(stn + ss[s0]);
            float e1 = edge_e(stn + ss[s1]);
            den += e0 + e1;
            uint4 p0 = *(const uint4*)(H + ((unsigned)s0 << 7) + l * 8);
            uint4 p1 = *(const uint4*)(H + ((unsigned)s1 << 7) + l * 8);
            float2v E0 = {e0, e0}, E1 = {e1, e1};
            acc2[0] += E0 * up2(p0.x) + E1 * up2(p1.x);
            acc2[1] += E0 * up2(p0.y) + E1 * up2(p1.y);
            acc2[2] += E0 * up2(p0.z) + E1 * up2(p1.z);
            acc2[3] += E0 * up2(p0.w) + E1 * up2(p1.w);
        }
        if (m < end) {
            int s0 = sortedLoc[m];
            float e0 = edge_e(stn + ss[s0]);
            den += e0;
            uint4 p0 = *(const uint4*)(H + ((unsigned)s0 << 7) + l * 8);
            float2v E0 = {e0, e0};
            acc2[0] += E0 * up2(p0.x);
            acc2[1] += E0 * up2(p0.y);
            acc2[2] += E0 * up2(p0.z);
            acc2[3] += E0 * up2(p0.w);
        }
        den += __shfl_xor(den, 16);
        den += __shfl_xor(den, 32);
        float r[8];
#pragma unroll
        for (int j = 0; j < 4; j++) {
            float a0 = acc2[j].x, a1 = acc2[j].y;
            a0 += __shfl_xor(a0, 16); a0 += __shfl_xor(a0, 32);
            a1 += __shfl_xor(a1, 16); a1 += __shfl_xor(a1, 32);
            r[j * 2] = a0; r[j * 2 + 1] = a1;
        }
        float inv = 1.0f / (den + 1e-9f);
        if (g == 0) {                               // 16 lanes store 512B row
            float4 o0 = make_float4(r[0] * inv, r[1] * inv, r[2] * inv, r[3] * inv);
            float4 o1 = make_float4(r[4] * inv, r[5] * inv, r[6] * inv, r[7] * inv);
            *(float4*)(out + (size_t)gnode * D + l * 8) = o0;
            *(float4*)(out + (size_t)gnode * D + l * 8 + 4) = o1;
        }
    }
}

extern "C" void kernel_launch(void* const* d_in, const int* in_sizes, int n_in,
                              void* d_out, int out_size, void* d_ws, size_t ws_size,
                              hipStream_t stream) {
    const float* X  = (const float*)d_in[0];
    const int*   E  = (const int*)d_in[1];
    const float* W  = (const float*)d_in[2];
    const float* KA = (const float*)d_in[3];
    for (int i = 0; i < n_in; i++) {
        int s = in_sizes[i];
        if (s == N_NODES * D)      X  = (const float*)d_in[i];
        else if (s == N_EDGES * 2) E  = (const int*)d_in[i];
        else if (s == D * D)       W  = (const float*)d_in[i];
        else if (s == 2 * D)       KA = (const float*)d_in[i];
    }
    float* out = (float*)d_out;                // fp32 [100000,128]; no aliasing

    char* ws = (char*)d_ws;
    // workspace layout (16B aligned), total 33,615,840 B (<= proven 33.64 MB)
    ushort_t* H        = (ushort_t*)(ws + 0);           // 25,600,000 B (bf16 h)
    float*    wa       = (float*)   (ws + 25600000);    //      1,024 B
    float*    st       = (float*)   (ws + 25601024);    //    400,000 B
    float*    ssb      = (float*)   (ws + 26001024);    //    400,000 B
    int*      sortedE  = (int*)     (ws + 26401024);    //  6,400,000 B
    ushort_t* bmat     = (ushort_t*)(ws + 32801024);    //    391,000 B
    ushort_t* lofs     = (ushort_t*)(ws + 33192032);    //    391,000 B
    int*      eflag    = (int*)     (ws + 33583040);    //         16 B
    ushort_t* WT       = (ushort_t*)(ws + 33583072);    //     32,768 B

    prep_kernel<<<66, 256, 0, stream>>>(W, KA, wa, WT, E, eflag);
    mega1_kernel<<<NBP + NB_B1, 256, 0, stream>>>(X, WT, wa, H, st, ssb,
                                                  N_NODES, E, eflag,
                                                  sortedE, bmat, lofs);
    agg2_kernel<<<BUCKETS, 512, 0, stream>>>(bmat, lofs, sortedE, st, ssb,
                                             H, out);
}

// Round 8
// 227.282 us; speedup vs baseline: 1.3186x; 1.0113x over previous
//
#include <hip/hip_runtime.h>
#include <stdint.h>

typedef unsigned short ushort_t;
typedef __attribute__((ext_vector_type(8))) short short8;   // 8 bf16 = 4 VGPRs
typedef __attribute__((ext_vector_type(4))) float float4v;  // MFMA acc
typedef __attribute__((ext_vector_type(2))) float float2v;  // packed f32 pair

#define N_NODES 100000
#define N_EDGES 1600000
#define D 128
#define NB_GEMM 1563   // (N_NODES+63)/64 tiles of 64 rows
#define NBP     782    // persistent gemm blocks: tiles b and b+782
#define NB_B1   250    // edge-bucket blocks
#define EPB     6400   // edges per B1 block: 250*6400 = 1,600,000 = 25*256 each
#define BUCKETS 782    // ceil(100000/128), 128 nodes per bucket
#define CAP     2560   // per-bucket edge capacity (mean 2046, sd 45 -> 11 sigma)

static __device__ __forceinline__ float2v up2(uint32_t u) {  // 2 bf16 -> 2 f32
    float2v r;
    r.x = __builtin_bit_cast(float, u << 16);
    r.y = __builtin_bit_cast(float, u & 0xffff0000u);
    return r;
}
static __device__ __forceinline__ uint32_t f2bf_u(float f) {
    uint32_t u = __builtin_bit_cast(uint32_t, f);
    return (u + 0x7fffu + ((u >> 16) & 1u)) >> 16;           // RNE
}
static __device__ __forceinline__ ushort_t f2bf(float f) {
    return (ushort_t)f2bf_u(f);
}
static __device__ __forceinline__ uint32_t pack2(float a, float b) {
    return f2bf_u(a) | (f2bf_u(b) << 16);
}
// leaky_relu(0.2) -> clip(-2,2) -> exp
static __device__ __forceinline__ float edge_e(float s) {
    float x = (s >= 0.0f) ? s : 0.2f * s;
    x = fminf(fmaxf(x, -2.0f), 2.0f);
    return __expf(x);
}

// ---------------- prep: W -> fragment-ordered bf16 WT | detect | wa ----------
__global__ void __launch_bounds__(256) prep_kernel(const float* __restrict__ W,
                                                   const float* __restrict__ KA,
                                                   float* __restrict__ wa,
                                                   ushort_t* __restrict__ WT,
                                                   const int* __restrict__ E,
                                                   int* __restrict__ eflag) {
    __shared__ int s;
    int b = blockIdx.x, t = threadIdx.x;
    int i = b * 256 + t;
    if (b < 64) {                                   // fragment-order + bf16
        int k = i >> 7, nn = i & 127;
        int kb = k >> 5, q = (k >> 3) & 3, j = k & 7;
        int tt = nn >> 4, l = nn & 15;
        WT[((kb * 8 + tt) * 64 + q * 16 + l) * 8 + j] = f2bf(W[i]);
    } else if (b == 64) {                           // edge dtype detect
        if (t == 0) s = 0;
        __syncthreads();
        int nz = 0;
#pragma unroll
        for (int j = 0; j < 8; j++)
            if (E[(t + j * 256) * 2 + 1] != 0) nz = 1;
        if (nz) atomicOr(&s, 1);
        __syncthreads();
        if (t == 0) *eflag = (s == 0) ? 1 : 0;
    } else if (b == 65) {                           // wa = W @ ka (fp32 exact)
        int half = t >> 7, k = t & 127;
        const float* kav = KA + half * 128;
        const float* wrow = W + k * 128;
        float acc = 0.0f;
#pragma unroll 8
        for (int j = 0; j < 128; j++) acc += wrow[j] * kav[j];
        wa[half * 128 + k] = acc;
    }
}

// ---------------- mega1: [0..781] persistent MFMA gemm (2 tiles, prefetch) ---
//                  [782..1031] B1: per-block bucket sort of edges (LDS only) --
// H row layout is PACKED-PAIR order: element e of a row = logical col
// e*16 + (lane that stored it); producer stores acc pairs directly (no LDS),
// consumer (agg2) unpacks with the matching mapping.
__global__ void __launch_bounds__(256) mega1_kernel(const float* __restrict__ X,
                                                    const ushort_t* __restrict__ WT,
                                                    const float* __restrict__ wa,
                                                    ushort_t* __restrict__ H,
                                                    float* __restrict__ st,
                                                    float* __restrict__ ss,
                                                    int M,
                                                    const int* __restrict__ E,
                                                    const int* __restrict__ eflag,
                                                    int* __restrict__ sortedE,
                                                    ushort_t* __restrict__ bmat,
                                                    ushort_t* __restrict__ lofs) {
    __shared__ int lds_b1[1280];                    // 5 KB: B1 branch only
    if (blockIdx.x >= NBP) {
        // ------------- B1: bucket-sort 6400 edges by tgt>>7, LDS atomics only
        int eb = blockIdx.x - NBP;
        int t = threadIdx.x;
        int* lhist = lds_b1;                        // [1024] (782 used)
        int* lpart = lds_b1 + 1024;                 // [256]
        for (int j = t; j < 1024; j += 256) lhist[j] = 0;
        __syncthreads();
        int i64 = *eflag;                           // wave-uniform
        int base = eb * EPB;
        // pass 1: count buckets (25*256 = 6400 = EPB exactly)
        for (int j = 0; j < 25; j++) {
            int i = base + j * 256 + t;
            int tgt = i64 ? E[i * 4] : E[i * 2];
            if ((unsigned)tgt >= (unsigned)N_NODES) tgt = 0;
            atomicAdd(&lhist[tgt >> 7], 1);
        }
        __syncthreads();
        // per-thread 4 bins -> block scan
        int c0 = lhist[t * 4], c1 = lhist[t * 4 + 1];
        int c2 = lhist[t * 4 + 2], c3 = lhist[t * 4 + 3];
        int sum = c0 + c1 + c2 + c3;
        lpart[t] = sum;
        __syncthreads();
        for (int off = 1; off < 256; off <<= 1) {   // Hillis-Steele inclusive
            int x = (t >= off) ? lpart[t - off] : 0;
            __syncthreads();
            lpart[t] += x;
            __syncthreads();
        }
        int e0 = lpart[t] - sum;                    // exclusive base of bin 4t
        int e1 = e0 + c0, e2 = e1 + c1, e3 = e2 + c2;
        int cc[4] = {c0, c1, c2, c3};
        int ee[4] = {e0, e1, e2, e3};
#pragma unroll
        for (int k = 0; k < 4; k++) {
            int bb = t * 4 + k;
            if (bb < BUCKETS) {
                bmat[eb * BUCKETS + bb] = (ushort_t)cc[k];
                lofs[eb * BUCKETS + bb] = (ushort_t)ee[k];
            }
        }
        // lhist becomes the placement cursor (own slots, no cross-thread reads)
        lhist[t * 4] = e0; lhist[t * 4 + 1] = e1;
        lhist[t * 4 + 2] = e2; lhist[t * 4 + 3] = e3;
        __syncthreads();
        // pass 2: place packed (tgt_local<<17)|src into block window
        for (int j = 0; j < 25; j++) {
            int i = base + j * 256 + t;
            int tgt, src;
            if (i64) { tgt = E[i * 4]; src = E[i * 4 + 2]; }
            else     { tgt = E[i * 2]; src = E[i * 2 + 1]; }
            if ((unsigned)tgt >= (unsigned)N_NODES) tgt = 0;
            if ((unsigned)src >= (unsigned)N_NODES) src = 0;
            int pos = atomicAdd(&lhist[tgt >> 7], 1);
            if (pos < EPB) sortedE[base + pos] = ((tgt & 127) << 17) | src;
        }
        return;
    }
    // -------- gemm branch: 2 tiles per block, next-tile X prefetched --------
    // No LDS: accumulators stored directly in packed-pair row order.
    int tid = threadIdx.x;
    int wave = tid >> 6, lane = tid & 63;
    int quad = lane >> 4, l16 = lane & 15;
    const short8* Bf = (const short8*)WT;     // 32 KB, L1/L2-resident

    int t0 = blockIdx.x;
    int nt = (t0 + NBP < NB_GEMM) ? 2 : 1;

    float4 f[8];                              // current tile X (A rows)
    {
        int ar = t0 * 64 + wave * 16 + l16; if (ar >= M) ar = M - 1;
        const float* xr = X + (size_t)ar * D + quad * 8;
#pragma unroll
        for (int kb = 0; kb < 4; kb++) {
            f[kb * 2]     = *(const float4*)(xr + kb * 32);
            f[kb * 2 + 1] = *(const float4*)(xr + kb * 32 + 4);
        }
    }
    for (int it = 0; it < nt; it++) {
        int m0 = (t0 + it * NBP) * 64 + wave * 16;
        float4 nf[8];
        if (it + 1 < nt) {                    // prefetch next tile's X now
            int ar = (t0 + NBP) * 64 + wave * 16 + l16; if (ar >= M) ar = M - 1;
            const float* xr = X + (size_t)ar * D + quad * 8;
#pragma unroll
            for (int kb = 0; kb < 4; kb++) {
                nf[kb * 2]     = *(const float4*)(xr + kb * 32);
                nf[kb * 2 + 1] = *(const float4*)(xr + kb * 32 + 4);
            }
        }
        // fused scores (fp32 exact) + bf16 cvt
        short8 a[4];
        float sct = 0.0f, scs = 0.0f;
#pragma unroll
        for (int kb = 0; kb < 4; kb++) {      // A[m=l16][k=kb*32+quad*8+j]
            float4 f0 = f[kb * 2], f1 = f[kb * 2 + 1];
            const float* wt0 = wa + kb * 32 + quad * 8;
            float4 t0v = *(const float4*)(wt0);
            float4 t1v = *(const float4*)(wt0 + 4);
            float4 s0v = *(const float4*)(wt0 + 128);
            float4 s1v = *(const float4*)(wt0 + 132);
            sct += f0.x * t0v.x + f0.y * t0v.y + f0.z * t0v.z + f0.w * t0v.w
                 + f1.x * t1v.x + f1.y * t1v.y + f1.z * t1v.z + f1.w * t1v.w;
            scs += f0.x * s0v.x + f0.y * s0v.y + f0.z * s0v.z + f0.w * s0v.w
                 + f1.x * s1v.x + f1.y * s1v.y + f1.z * s1v.z + f1.w * s1v.w;
            short8 v;
            v[0] = (short)f2bf(f0.x); v[1] = (short)f2bf(f0.y);
            v[2] = (short)f2bf(f0.z); v[3] = (short)f2bf(f0.w);
            v[4] = (short)f2bf(f1.x); v[5] = (short)f2bf(f1.y);
            v[6] = (short)f2bf(f1.z); v[7] = (short)f2bf(f1.w);
            a[kb] = v;
        }
        sct += __shfl_xor(sct, 16); sct += __shfl_xor(sct, 32);
        scs += __shfl_xor(scs, 16); scs += __shfl_xor(scs, 32);
        if (quad == 0 && m0 + l16 < M) { st[m0 + l16] = sct; ss[m0 + l16] = scs; }

        float4v acc[8] = {};
#pragma unroll
        for (int kb = 0; kb < 4; kb++) {
#pragma unroll
            for (int t = 0; t < 8; t++) {     // B[k=kb*32+quad*8+j][n=t*16+l16]
                short8 b = Bf[(kb * 8 + t) * 64 + lane];
                acc[t] = __builtin_amdgcn_mfma_f32_16x16x32_bf16(a[kb], b, acc[t], 0, 0, 0);
            }
        }
        // C/D: col = t*16 + l16, row = quad*4 + r   [m89-verified]
        // direct packed-pair store: element l16*8 + 2j + hi  <->  col (2j+hi)*16+l16
#pragma unroll
        for (int r = 0; r < 4; r++) {
            int orow = m0 + quad * 4 + r;
            if (orow < M) {
                uint4 v;
                v.x = pack2(acc[0][r], acc[1][r]);
                v.y = pack2(acc[2][r], acc[3][r]);
                v.z = pack2(acc[4][r], acc[5][r]);
                v.w = pack2(acc[6][r], acc[7][r]);
                *(uint4*)(H + (size_t)orow * D + l16 * 8) = v;
            }
        }
        if (it + 1 < nt) {
#pragma unroll
            for (int j = 0; j < 8; j++) f[j] = nf[j];
        }
    }
}

// ---------------- agg2: fused CSR-build + aggregation, 1 block = 1 bucket ----
// Phase A: shfl-scan 250 window-counts, gather edges to LDS, hist+scan+place.
// Phase B: 8 waves x 16 nodes, 4 edge-slot groups/wave, unroll-2 gather of H.
__global__ void __launch_bounds__(512) agg2_kernel(const ushort_t* __restrict__ bmat,
                                                   const ushort_t* __restrict__ lofs,
                                                   const int* __restrict__ sortedE,
                                                   const float* __restrict__ st,
                                                   const float* __restrict__ ss,
                                                   const ushort_t* __restrict__ H,
                                                   float* __restrict__ out) {
    __shared__ int stage[CAP];
    __shared__ int sortedLoc[CAP];
    __shared__ int lh[128];
    __shared__ int lrp[129];
    __shared__ int wsum[8];
    int b = blockIdx.x, t = threadIdx.x;
    int lane = t & 63, wv = t >> 6;
    // ---- Phase A1: exclusive scan of 250 window counts (shfl, 1 barrier) ---
    int cnt = 0, sst = 0;
    if (t < NB_B1) {
        cnt = bmat[t * BUCKETS + b];
        sst = lofs[t * BUCKETS + b];
    }
    int x = cnt;
#pragma unroll
    for (int off = 1; off < 64; off <<= 1) {        // wave inclusive scan
        int y = __shfl_up(x, off);
        if (lane >= off) x += y;
    }
    if (lane == 63) wsum[wv] = x;
    if (t < 128) lh[t] = 0;
    __syncthreads();
    int wbase = 0, total = 0;
#pragma unroll
    for (int w = 0; w < 8; w++) {
        int sv = wsum[w];
        if (w < wv) wbase += sv;
        total += sv;
    }
    if (total > CAP) total = CAP;                   // 11-sigma guard
    int soff = wbase + x - cnt;                     // staging offset
    for (int k = 0; k < cnt; k++) {                 // gather my segment
        int idx = soff + k;
        if (idx < CAP) stage[idx] = sortedE[t * EPB + sst + k];
    }
    __syncthreads();
    // ---- Phase A2: histogram over 128 local nodes --------------------------
    for (int j = t; j < total; j += 512)
        atomicAdd(&lh[stage[j] >> 17], 1);
    __syncthreads();
    // ---- Phase A3: scan hist -> local rowp (shfl over waves 0-1) -----------
    int v = (t < 128) ? lh[t] : 0;
    int xs = v;
#pragma unroll
    for (int off = 1; off < 64; off <<= 1) {
        int y = __shfl_up(xs, off);
        if (lane >= off) xs += y;
    }
    if (t == 63) wsum[0] = xs;                      // wave0 total
    __syncthreads();
    if (t < 128) {
        int inc = (wv == 1) ? xs + wsum[0] : xs;
        int ex = inc - v;
        lrp[t] = ex;
        lh[t]  = ex;                                // placement cursor
    }
    if (t == 0) lrp[128] = total;
    __syncthreads();
    for (int j = t; j < total; j += 512) {          // place sorted-by-node
        int p = stage[j];
        int pos = atomicAdd(&lh[p >> 17], 1);
        if (pos < total) sortedLoc[pos] = p & 0x1FFFF;
    }
    __syncthreads();
    // ---------------- Phase B: aggregate from LDS-sorted edges --------------
    int g = lane >> 4, l = lane & 15;
    for (int nd = wv; nd < 128; nd += 8) {
        int gnode = b * 128 + nd;
        if (gnode >= N_NODES) break;                // only bucket 781 tail
        int start = lrp[nd], end = lrp[nd + 1];
        float stn = st[gnode];
        float den = 0.0f;
        float2v acc2[4] = {};
        int m = start + g;
        for (; m + 4 < end; m += 8) {               // 2 chains in flight/group
            int s0 = sortedLoc[m], s1 = sortedLoc[m + 4];
            float e0 = edge_e(stn + ss[s0]);
            float e1 = edge_e(stn + ss[s1]);
            den += e0 + e1;
            uint4 p0 = *(const uint4*)(H + ((unsigned)s0 << 7) + l * 8);
            uint4 p1 = *(const uint4*)(H + ((unsigned)s1 << 7) + l * 8);
            float2v E0 = {e0, e0}, E1 = {e1, e1};
            acc2[0] += E0 * up2(p0.x) + E1 * up2(p1.x);
            acc2[1] += E0 * up2(p0.y) + E1 * up2(p1.y);
            acc2[2] += E0 * up2(p0.z) + E1 * up2(p1.z);
            acc2[3] += E0 * up2(p0.w) + E1 * up2(p1.w);
        }
        if (m < end) {
            int s0 = sortedLoc[m];
            float e0 = edge_e(stn + ss[s0]);
            den += e0;
            uint4 p0 = *(const uint4*)(H + ((unsigned)s0 << 7) + l * 8);
            float2v E0 = {e0, e0};
            acc2[0] += E0 * up2(p0.x);
            acc2[1] += E0 * up2(p0.y);
            acc2[2] += E0 * up2(p0.z);
            acc2[3] += E0 * up2(p0.w);
        }
        den += __shfl_xor(den, 16);
        den += __shfl_xor(den, 32);
        float r[8];
#pragma unroll
        for (int j = 0; j < 4; j++) {
            float a0 = acc2[j].x, a1 = acc2[j].y;
            a0 += __shfl_xor(a0, 16); a0 += __shfl_xor(a0, 32);
            a1 += __shfl_xor(a1, 16); a1 += __shfl_xor(a1, 32);
            r[j * 2] = a0; r[j * 2 + 1] = a1;
        }
        float inv = 1.0f / (den + 1e-9f);
        if (g == 0) {
            // packed-pair H layout: r[k] holds logical col k*16 + l.
            // 16 lanes x stride-16 cols -> 8 x 64B contiguous stores per node.
#pragma unroll
            for (int k = 0; k < 8; k++)
                out[(size_t)gnode * D + k * 16 + l] = r[k] * inv;
        }
    }
}

extern "C" void kernel_launch(void* const* d_in, const int* in_sizes, int n_in,
                              void* d_out, int out_size, void* d_ws, size_t ws_size,
                              hipStream_t stream) {
    const float* X  = (const float*)d_in[0];
    const int*   E  = (const int*)d_in[1];
    const float* W  = (const float*)d_in[2];
    const float* KA = (const float*)d_in[3];
    for (int i = 0; i < n_in; i++) {
        int s = in_sizes[i];
        if (s == N_NODES * D)      X  = (const float*)d_in[i];
        else if (s == N_EDGES * 2) E  = (const int*)d_in[i];
        else if (s == D * D)       W  = (const float*)d_in[i];
        else if (s == 2 * D)       KA = (const float*)d_in[i];
    }
    float* out = (float*)d_out;                // fp32 [100000,128]; no aliasing

    char* ws = (char*)d_ws;
    // workspace layout (16B aligned), total 33,615,840 B (<= proven 33.64 MB)
    ushort_t* H        = (ushort_t*)(ws + 0);           // 25,600,000 B (bf16 h)
    float*    wa       = (float*)   (ws + 25600000);    //      1,024 B
    float*    st       = (float*)   (ws + 25601024);    //    400,000 B
    float*    ssb      = (float*)   (ws + 26001024);    //    400,000 B
    int*      sortedE  = (int*)     (ws + 26401024);    //  6,400,000 B
    ushort_t* bmat     = (ushort_t*)(ws + 32801024);    //    391,000 B
    ushort_t* lofs     = (ushort_t*)(ws + 33192032);    //    391,000 B
    int*      eflag    = (int*)     (ws + 33583040);    //         16 B
    ushort_t* WT       = (ushort_t*)(ws + 33583072);    //     32,768 B

    prep_kernel<<<66, 256, 0, stream>>>(W, KA, wa, WT, E, eflag);
    mega1_kernel<<<NBP + NB_B1, 256, 0, stream>>>(X, WT, wa, H, st, ssb,
                                                  N_NODES, E, eflag,
                                                  sortedE, bmat, lofs);
    agg2_kernel<<<BUCKETS, 512, 0, stream>>>(bmat, lofs, sortedE, st, ssb,
                                             H, out);
}

// Round 9
// 213.680 us; speedup vs baseline: 1.4026x; 1.0637x over previous
//
#include <hip/hip_runtime.h>
#include <stdint.h>

typedef unsigned short ushort_t;
typedef __attribute__((ext_vector_type(8))) short short8;   // 8 bf16 = 4 VGPRs
typedef __attribute__((ext_vector_type(4))) float float4v;  // MFMA acc
typedef __attribute__((ext_vector_type(2))) float float2v;  // packed f32 pair

#define N_NODES 100000
#define N_EDGES 1600000
#define D 128
#define NB_GEMM 1563   // (N_NODES+63)/64 tiles of 64 rows
#define NBP     782    // gemm blocks: tiles b and b+782
#define NB_B1   250    // edge-bucket blocks
#define EPB     6400   // edges per B1 block: 250*6400 = 1,600,000 = 25*256 each
#define BUCKETS 782    // ceil(100000/128), 128 nodes per bucket
#define CAP     2560   // per-bucket edge capacity (mean 2046, sd 45 -> 11 sigma)

static __device__ __forceinline__ float2v up2(uint32_t u) {  // 2 bf16 -> 2 f32
    float2v r;
    r.x = __builtin_bit_cast(float, u << 16);
    r.y = __builtin_bit_cast(float, u & 0xffff0000u);
    return r;
}
static __device__ __forceinline__ uint32_t f2bf_u(float f) {
    uint32_t u = __builtin_bit_cast(uint32_t, f);
    return (u + 0x7fffu + ((u >> 16) & 1u)) >> 16;           // RNE
}
static __device__ __forceinline__ ushort_t f2bf(float f) {
    return (ushort_t)f2bf_u(f);
}
static __device__ __forceinline__ uint32_t pack2(float a, float b) {
    return f2bf_u(a) | (f2bf_u(b) << 16);
}
// leaky_relu(0.2) -> clip(-2,2) -> exp
static __device__ __forceinline__ float edge_e(float s) {
    float x = (s >= 0.0f) ? s : 0.2f * s;
    x = fminf(fmaxf(x, -2.0f), 2.0f);
    return __expf(x);
}

// ---------------- prep: W -> fragment-ordered bf16 WT | detect | wa ----------
__global__ void __launch_bounds__(256) prep_kernel(const float* __restrict__ W,
                                                   const float* __restrict__ KA,
                                                   float* __restrict__ wa,
                                                   ushort_t* __restrict__ WT,
                                                   const int* __restrict__ E,
                                                   int* __restrict__ eflag) {
    __shared__ int s;
    int b = blockIdx.x, t = threadIdx.x;
    int i = b * 256 + t;
    if (b < 64) {                                   // fragment-order + bf16
        int k = i >> 7, nn = i & 127;
        int kb = k >> 5, q = (k >> 3) & 3, j = k & 7;
        int tt = nn >> 4, l = nn & 15;
        WT[((kb * 8 + tt) * 64 + q * 16 + l) * 8 + j] = f2bf(W[i]);
    } else if (b == 64) {                           // edge dtype detect
        if (t == 0) s = 0;
        __syncthreads();
        int nz = 0;
#pragma unroll
        for (int j = 0; j < 8; j++)
            if (E[(t + j * 256) * 2 + 1] != 0) nz = 1;
        if (nz) atomicOr(&s, 1);
        __syncthreads();
        if (t == 0) *eflag = (s == 0) ? 1 : 0;
    } else if (b == 65) {                           // wa = W @ ka (fp32 exact)
        int half = t >> 7, k = t & 127;
        const float* kav = KA + half * 128;
        const float* wrow = W + k * 128;
        float acc = 0.0f;
#pragma unroll 8
        for (int j = 0; j < 128; j++) acc += wrow[j] * kav[j];
        wa[half * 128 + k] = acc;
    }
}

// ---------------- b1: per-block bucket sort of 6400 edges (LDS atomics) ------
// uint4/uint2 vector edge loads; edges register-cached across the two passes.
__global__ void __launch_bounds__(256) b1_kernel(const int* __restrict__ E,
                                                 const int* __restrict__ eflag,
                                                 int* __restrict__ sortedE,
                                                 ushort_t* __restrict__ bmat,
                                                 ushort_t* __restrict__ lofs) {
    __shared__ int lhist[1024];                     // 782 used
    __shared__ int lpart[256];
    int eb = blockIdx.x, t = threadIdx.x;
    for (int j = t; j < 1024; j += 256) lhist[j] = 0;
    __syncthreads();
    int i64 = *eflag;                               // wave-uniform
    int base = eb * EPB;
    int bin[25], w[25];                             // static-indexed (unrolled)
#pragma unroll
    for (int j = 0; j < 25; j++) {
        int i = base + j * 256 + t;
        int tgt, src;
        if (i64) { uint4 v = *(const uint4*)(E + (size_t)i * 4); tgt = (int)v.x; src = (int)v.z; }
        else     { uint2 v = *(const uint2*)(E + (size_t)i * 2); tgt = (int)v.x; src = (int)v.y; }
        if ((unsigned)tgt >= (unsigned)N_NODES) tgt = 0;
        if ((unsigned)src >= (unsigned)N_NODES) src = 0;
        bin[j] = tgt >> 7;
        w[j]   = ((tgt & 127) << 17) | src;
        atomicAdd(&lhist[bin[j]], 1);
    }
    __syncthreads();
    // per-thread 4 bins -> block scan
    int c0 = lhist[t * 4], c1 = lhist[t * 4 + 1];
    int c2 = lhist[t * 4 + 2], c3 = lhist[t * 4 + 3];
    int sum = c0 + c1 + c2 + c3;
    lpart[t] = sum;
    __syncthreads();
    for (int off = 1; off < 256; off <<= 1) {       // Hillis-Steele inclusive
        int x = (t >= off) ? lpart[t - off] : 0;
        __syncthreads();
        lpart[t] += x;
        __syncthreads();
    }
    int e0 = lpart[t] - sum;                        // exclusive base of bin 4t
    int e1 = e0 + c0, e2 = e1 + c1, e3 = e2 + c2;
    int cc[4] = {c0, c1, c2, c3};
    int ee[4] = {e0, e1, e2, e3};
#pragma unroll
    for (int k = 0; k < 4; k++) {
        int bb = t * 4 + k;
        if (bb < BUCKETS) {
            bmat[eb * BUCKETS + bb] = (ushort_t)cc[k];
            lofs[eb * BUCKETS + bb] = (ushort_t)ee[k];
        }
    }
    // lhist becomes the placement cursor (own slots, no cross-thread reads)
    lhist[t * 4] = e0; lhist[t * 4 + 1] = e1;
    lhist[t * 4 + 2] = e2; lhist[t * 4 + 3] = e3;
    __syncthreads();
    // pass 2 entirely from registers
#pragma unroll
    for (int j = 0; j < 25; j++) {
        int pos = atomicAdd(&lhist[bin[j]], 1);
        if (pos < EPB) sortedE[base + pos] = w[j];
    }
}

// ---------------- gemm: persistent MFMA gemm (2 tiles, X prefetch, LDS B) ----
// H row layout is PACKED-PAIR order: element l16*8+2j+hi <-> col (2j+hi)*16+l16.
__global__ void __launch_bounds__(256) gemm_kernel(const float* __restrict__ X,
                                                   const ushort_t* __restrict__ WT,
                                                   const float* __restrict__ wa,
                                                   ushort_t* __restrict__ H,
                                                   float* __restrict__ st,
                                                   float* __restrict__ ss,
                                                   int M) {
    __shared__ ushort_t lds_wt[16384];              // 32 KB fragment-order copy
    int tid = threadIdx.x;
    {
        const uint4* srcp = (const uint4*)WT;       // 2048 x 16B
        uint4* dstp = (uint4*)lds_wt;
        for (int j = tid; j < 2048; j += 256) dstp[j] = srcp[j];
    }
    __syncthreads();

    int wave = tid >> 6, lane = tid & 63;
    int quad = lane >> 4, l16 = lane & 15;
    int t0 = blockIdx.x;
    int nt = (t0 + NBP < NB_GEMM) ? 2 : 1;

    float4 f[8];                                    // current tile X (A rows)
    {
        int ar = t0 * 64 + wave * 16 + l16; if (ar >= M) ar = M - 1;
        const float* xr = X + (size_t)ar * D + quad * 8;
#pragma unroll
        for (int kb = 0; kb < 4; kb++) {
            f[kb * 2]     = *(const float4*)(xr + kb * 32);
            f[kb * 2 + 1] = *(const float4*)(xr + kb * 32 + 4);
        }
    }
    for (int it = 0; it < nt; it++) {
        int m0 = (t0 + it * NBP) * 64 + wave * 16;
        float4 nf[8];
        if (it + 1 < nt) {                          // prefetch next tile's X
            int ar = (t0 + NBP) * 64 + wave * 16 + l16; if (ar >= M) ar = M - 1;
            const float* xr = X + (size_t)ar * D + quad * 8;
#pragma unroll
            for (int kb = 0; kb < 4; kb++) {
                nf[kb * 2]     = *(const float4*)(xr + kb * 32);
                nf[kb * 2 + 1] = *(const float4*)(xr + kb * 32 + 4);
            }
        }
        // fused scores (fp32 exact) + bf16 cvt
        short8 a[4];
        float sct = 0.0f, scs = 0.0f;
#pragma unroll
        for (int kb = 0; kb < 4; kb++) {            // A[m=l16][k=kb*32+quad*8+j]
            float4 f0 = f[kb * 2], f1 = f[kb * 2 + 1];
            const float* wt0 = wa + kb * 32 + quad * 8;
            float4 t0v = *(const float4*)(wt0);
            float4 t1v = *(const float4*)(wt0 + 4);
            float4 s0v = *(const float4*)(wt0 + 128);
            float4 s1v = *(const float4*)(wt0 + 132);
            sct += f0.x * t0v.x + f0.y * t0v.y + f0.z * t0v.z + f0.w * t0v.w
                 + f1.x * t1v.x + f1.y * t1v.y + f1.z * t1v.z + f1.w * t1v.w;
            scs += f0.x * s0v.x + f0.y * s0v.y + f0.z * s0v.z + f0.w * s0v.w
                 + f1.x * s1v.x + f1.y * s1v.y + f1.z * s1v.z + f1.w * s1v.w;
            short8 v;
            v[0] = (short)f2bf(f0.x); v[1] = (short)f2bf(f0.y);
            v[2] = (short)f2bf(f0.z); v[3] = (short)f2bf(f0.w);
            v[4] = (short)f2bf(f1.x); v[5] = (short)f2bf(f1.y);
            v[6] = (short)f2bf(f1.z); v[7] = (short)f2bf(f1.w);
            a[kb] = v;
        }
        sct += __shfl_xor(sct, 16); sct += __shfl_xor(sct, 32);
        scs += __shfl_xor(scs, 16); scs += __shfl_xor(scs, 32);
        if (quad == 0 && m0 + l16 < M) { st[m0 + l16] = sct; ss[m0 + l16] = scs; }

        float4v acc[8] = {};
#pragma unroll
        for (int kb = 0; kb < 4; kb++) {
#pragma unroll
            for (int t = 0; t < 8; t++) {           // B[k=kb*32+quad*8+j][n=t*16+l16]
                short8 b = *(const short8*)(&lds_wt[((kb * 8 + t) * 64 + lane) * 8]);
                acc[t] = __builtin_amdgcn_mfma_f32_16x16x32_bf16(a[kb], b, acc[t], 0, 0, 0);
            }
        }
        // C/D: col = t*16 + l16, row = quad*4 + r   [m89-verified]
#pragma unroll
        for (int r = 0; r < 4; r++) {
            int orow = m0 + quad * 4 + r;
            if (orow < M) {
                uint4 v;
                v.x = pack2(acc[0][r], acc[1][r]);
                v.y = pack2(acc[2][r], acc[3][r]);
                v.z = pack2(acc[4][r], acc[5][r]);
                v.w = pack2(acc[6][r], acc[7][r]);
                *(uint4*)(H + (size_t)orow * D + l16 * 8) = v;
            }
        }
        if (it + 1 < nt) {
#pragma unroll
            for (int j = 0; j < 8; j++) f[j] = nf[j];
        }
    }
}

// ---------------- agg2: fused CSR-build + aggregation, 1 block = 1 bucket ----
// Phase A: shfl-scan; FLAT coalesced gather via binary search; hist+scan+place.
// Phase B: 8 waves x 16 nodes, 4 edge-slot groups/wave, unroll-4 gather of H.
__global__ void __launch_bounds__(512) agg2_kernel(const ushort_t* __restrict__ bmat,
                                                   const ushort_t* __restrict__ lofs,
                                                   const int* __restrict__ sortedE,
                                                   const float* __restrict__ st,
                                                   const float* __restrict__ ss,
                                                   const ushort_t* __restrict__ H,
                                                   float* __restrict__ out) {
    __shared__ int stage[CAP];
    __shared__ int sortedLoc[CAP];
    __shared__ int lh[128];
    __shared__ int lrp[129];
    __shared__ int wsum[8];
    __shared__ int lsoff[NB_B1];
    __shared__ int lsst[NB_B1];
    int b = blockIdx.x, t = threadIdx.x;
    int lane = t & 63, wv = t >> 6;
    // ---- Phase A1: exclusive scan of 250 window counts (shfl) --------------
    int cnt = 0, sst = 0;
    if (t < NB_B1) {
        cnt = bmat[t * BUCKETS + b];
        sst = lofs[t * BUCKETS + b];
    }
    int x = cnt;
#pragma unroll
    for (int off = 1; off < 64; off <<= 1) {        // wave inclusive scan
        int y = __shfl_up(x, off);
        if (lane >= off) x += y;
    }
    if (lane == 63) wsum[wv] = x;
    if (t < 128) lh[t] = 0;
    __syncthreads();
    int wbase = 0, total = 0;
#pragma unroll
    for (int w = 0; w < 8; w++) {
        int sv = wsum[w];
        if (w < wv) wbase += sv;
        total += sv;
    }
    if (total > CAP) total = CAP;                   // 11-sigma guard
    int soff = wbase + x - cnt;                     // staging offset (exclusive)
    if (t < NB_B1) { lsoff[t] = soff; lsst[t] = sst; }
    __syncthreads();
    // ---- flat coalesced gather: thread j pulls stage[j] --------------------
    for (int j = t; j < total; j += 512) {
        int lo = 0, hi = NB_B1 - 1;                 // largest w: lsoff[w] <= j
        while (lo < hi) {
            int mid = (lo + hi + 1) >> 1;
            if (lsoff[mid] <= j) lo = mid; else hi = mid - 1;
        }
        stage[j] = sortedE[lo * EPB + lsst[lo] + (j - lsoff[lo])];
    }
    __syncthreads();
    // ---- Phase A2: histogram over 128 local nodes --------------------------
    for (int j = t; j < total; j += 512)
        atomicAdd(&lh[stage[j] >> 17], 1);
    __syncthreads();
    // ---- Phase A3: scan hist -> local rowp (shfl over waves 0-1) -----------
    int v = (t < 128) ? lh[t] : 0;
    int xs = v;
#pragma unroll
    for (int off = 1; off < 64; off <<= 1) {
        int y = __shfl_up(xs, off);
        if (lane >= off) xs += y;
    }
    if (t == 63) wsum[0] = xs;                      // wave0 total
    __syncthreads();
    if (t < 128) {
        int inc = (wv == 1) ? xs + wsum[0] : xs;
        int ex = inc - v;
        lrp[t] = ex;
        lh[t]  = ex;                                // placement cursor
    }
    if (t == 0) lrp[128] = total;
    __syncthreads();
    for (int j = t; j < total; j += 512) {          // place sorted-by-node
        int p = stage[j];
        int pos = atomicAdd(&lh[p >> 17], 1);
        if (pos < total) sortedLoc[pos] = p & 0x1FFFF;
    }
    __syncthreads();
    // ---------------- Phase B: aggregate from LDS-sorted edges --------------
    int g = lane >> 4, l = lane & 15;
    for (int nd = wv; nd < 128; nd += 8) {
        int gnode = b * 128 + nd;
        if (gnode >= N_NODES) break;                // only bucket 781 tail
        int start = lrp[nd], end = lrp[nd + 1];
        float stn = st[gnode];
        float den = 0.0f;
        float2v acc2[4] = {};
        int m = start + g;
        for (; m + 12 < end; m += 16) {             // 4 chains in flight/group
            int s0 = sortedLoc[m],     s1 = sortedLoc[m + 4];
            int s2 = sortedLoc[m + 8], s3 = sortedLoc[m + 12];
            float e0 = edge_e(stn + ss[s0]);
            float e1 = edge_e(stn + ss[s1]);
            float e2 = edge_e(stn + ss[s2]);
            float e3 = edge_e(stn + ss[s3]);
            den += (e0 + e1) + (e2 + e3);
            uint4 p0 = *(const uint4*)(H + ((unsigned)s0 << 7) + l * 8);
            uint4 p1 = *(const uint4*)(H + ((unsigned)s1 << 7) + l * 8);
            uint4 p2 = *(const uint4*)(H + ((unsigned)s2 << 7) + l * 8);
            uint4 p3 = *(const uint4*)(H + ((unsigned)s3 << 7) + l * 8);
            float2v E0 = {e0, e0}, E1 = {e1, e1}, E2 = {e2, e2}, E3 = {e3, e3};
            acc2[0] += E0 * up2(p0.x) + E1 * up2(p1.x) + E2 * up2(p2.x) + E3 * up2(p3.x);
            acc2[1] += E0 * up2(p0.y) + E1 * up2(p1.y) + E2 * up2(p2.y) + E3 * up2(p3.y);
            acc2[2] += E0 * up2(p0.z) + E1 * up2(p1.z) + E2 * up2(p2.z) + E3 * up2(p3.z);
            acc2[3] += E0 * up2(p0.w) + E1 * up2(p1.w) + E2 * up2(p2.w) + E3 * up2(p3.w);
        }
        for (; m + 4 < end; m += 8) {               // 2-chain remainder
            int s0 = sortedLoc[m], s1 = sortedLoc[m + 4];
            float e0 = edge_e(stn + ss[s0]);
            float e1 = edge_e(stn + ss[s1]);
            den += e0 + e1;
            uint4 p0 = *(const uint4*)(H + ((unsigned)s0 << 7) + l * 8);
            uint4 p1 = *(const uint4*)(H + ((unsigned)s1 << 7) + l * 8);
            float2v E0 = {e0, e0}, E1 = {e1, e1};
            acc2[0] += E0 * up2(p0.x) + E1 * up2(p1.x);
            acc2[1] += E0 * up2(p0.y) + E1 * up2(p1.y);
            acc2[2] += E0 * up2(p0.z) + E1 * up2(p1.z);
            acc2[3] += E0 * up2(p0.w) + E1 * up2(p1.w);
        }
        if (m < end) {
            int s0 = sortedLoc[m];
            float e0 = edge_e(stn + ss[s0]);
            den += e0;
            uint4 p0 = *(const uint4*)(H + ((unsigned)s0 << 7) + l * 8);
            float2v E0 = {e0, e0};
            acc2[0] += E0 * up2(p0.x);
            acc2[1] += E0 * up2(p0.y);
            acc2[2] += E0 * up2(p0.z);
            acc2[3] += E0 * up2(p0.w);
        }
        den += __shfl_xor(den, 16);
        den += __shfl_xor(den, 32);
        float r[8];
#pragma unroll
        for (int j = 0; j < 4; j++) {
            float a0 = acc2[j].x, a1 = acc2[j].y;
            a0 += __shfl_xor(a0, 16); a0 += __shfl_xor(a0, 32);
            a1 += __shfl_xor(a1, 16); a1 += __shfl_xor(a1, 32);
            r[j * 2] = a0; r[j * 2 + 1] = a1;
        }
        float inv = 1.0f / (den + 1e-9f);
        if (g == 0) {
            // packed-pair H layout: r[k] holds logical col k*16 + l.
#pragma unroll
            for (int k = 0; k < 8; k++)
                out[(size_t)gnode * D + k * 16 + l] = r[k] * inv;
        }
    }
}

extern "C" void kernel_launch(void* const* d_in, const int* in_sizes, int n_in,
                              void* d_out, int out_size, void* d_ws, size_t ws_size,
                              hipStream_t stream) {
    const float* X  = (const float*)d_in[0];
    const int*   E  = (const int*)d_in[1];
    const float* W  = (const float*)d_in[2];
    const float* KA = (const float*)d_in[3];
    for (int i = 0; i < n_in; i++) {
        int s = in_sizes[i];
        if (s == N_NODES * D)      X  = (const float*)d_in[i];
        else if (s == N_EDGES * 2) E  = (const int*)d_in[i];
        else if (s == D * D)       W  = (const float*)d_in[i];
        else if (s == 2 * D)       KA = (const float*)d_in[i];
    }
    float* out = (float*)d_out;                // fp32 [100000,128]; no aliasing

    char* ws = (char*)d_ws;
    // workspace layout (16B aligned), total 33,615,840 B (<= proven 33.64 MB)
    ushort_t* H        = (ushort_t*)(ws + 0);           // 25,600,000 B (bf16 h)
    float*    wa       = (float*)   (ws + 25600000);    //      1,024 B
    float*    st       = (float*)   (ws + 25601024);    //    400,000 B
    float*    ssb      = (float*)   (ws + 26001024);    //    400,000 B
    int*      sortedE  = (int*)     (ws + 26401024);    //  6,400,000 B
    ushort_t* bmat     = (ushort_t*)(ws + 32801024);    //    391,000 B
    ushort_t* lofs     = (ushort_t*)(ws + 33192032);    //    391,000 B
    int*      eflag    = (int*)     (ws + 33583040);    //         16 B
    ushort_t* WT       = (ushort_t*)(ws + 33583072);    //     32,768 B

    prep_kernel<<<66, 256, 0, stream>>>(W, KA, wa, WT, E, eflag);
    b1_kernel<<<NB_B1, 256, 0, stream>>>(E, eflag, sortedE, bmat, lofs);
    gemm_kernel<<<NBP, 256, 0, stream>>>(X, WT, wa, H, st, ssb, N_NODES);
    agg2_kernel<<<BUCKETS, 512, 0, stream>>>(bmat, lofs, sortedE, st, ssb,
                                             H, out);
}